// Round 10
// baseline (689.305 us; speedup 1.0000x reference)
//
#include <hip/hip_runtime.h>

// DMPNN encoder, MI355X bf16-MFMA, round 16: revert r15 fusion (wave-0 scan
// serialized the GEMM block: 3/4 waves idle between barriers -> 125us) and
// move the ownership-scan idea into STANDALONE streaming segsums.
//
// Pipeline (pos-space, alternating e-/f-layout; identities:
//   fidx[p]=rev[eidx[p]], sidx[p]=dst[eidx[p]] (sorted),
//   pidx[p]=posOf[fidx[p]] fix-point-free involution):
//   k_init : persistent waves, Wi in LDS (96-stride 24-slot XOR), e-layout @pidx[p]
//   segsum1: segsum_s<false> streaming (e-layout rows sequential)
//   k_msg1 : tmp[sidx[p]] - h0@p -> h1 f-layout @p
//   segsum2: segsum_s<true> streaming (rows pidx[i], node sidx[i])
//   k_msg2 : tmp[sidx[p]] - h1@pidx[p] -> h2 e-layout @pidx[p]
//   segsum3: segsum_s<false> streaming
//   k_out  : persistent 16-node tiles (r14 form)
//
// segsum_s: wave owns pos-window [64w,64w+64). lane = u32 col -> one load
// instruction reads one full 256-B row. Node ids broadcast via __shfl from a
// preloaded per-lane register. Wave skips leading rows that continue a node
// owned by an earlier wave; sums serially, stores at node change; tail node
// extends past the window (chunked shfl loop). No atomics, every h row read
// exactly once, stores coalesced u32/lane. Zero-degree nodes: tmp memset
// once before segsum1 (degree>0 node set identical across all 3 passes).
//
// Weight channel permutation c(p) = (p&64) + 2*(p&15) + ((p>>4)&1) + 32*((p>>5)&1):
// acc pair (2a,2a+1) at lane ln = channels 32a+2ln, 32a+2ln+1; u32 col u holds
// channels 2u,2u+1 (natural order).

typedef unsigned int u32;
typedef unsigned short u16;
using bf16x8 = __attribute__((ext_vector_type(8))) __bf16;
using f32x4  = __attribute__((ext_vector_type(4))) float;

#define NN 50000
#define NP 400000
#define NE 800000
#define AF 133
#define HID 128
#define ATU 68      // atomBf row stride in u32
#define KPU1 80     // Wi packed row stride in u32 (160 cols = 5 kc chunks)
#define WHU 64      // Wh packed row stride (u32) = 256 B rows
#define KPU3 148    // Wo packed row stride; 144 data u32 = 288 cols = 9 chunks
#define KC3 9
#define NCH 196     // scan chunks of 256 covering NN

__device__ __forceinline__ u16 f2bf(float f) {
    union { float f; u32 u; } x; x.f = f;
    u32 r = x.u + 0x7fffu + ((x.u >> 16) & 1u);   // RNE
    return (u16)(r >> 16);
}
__device__ __forceinline__ float bf2f(u16 b) {
    union { u32 u; float f; } x; x.u = ((u32)b) << 16;
    return x.f;
}
__device__ __forceinline__ float lo16(u32 v) { return bf2f((u16)v); }
__device__ __forceinline__ float hi16(u32 v) { return bf2f((u16)(v >> 16)); }
__device__ __forceinline__ u32 pack2(float a, float b) {
    return (u32)f2bf(a) | ((u32)f2bf(b) << 16);
}
__device__ __forceinline__ float relu(float v) { return v > 0.f ? v : 0.f; }

// single-instruction RNE pack of two f32 -> packed bf16x2 (no builtin on gfx950)
__device__ __forceinline__ u32 cvt_pk_bf16(float lo, float hi) {
    u32 r;
    asm("v_cvt_pk_bf16_f32 %0, %1, %2" : "=v"(r) : "v"(lo), "v"(hi));
    return r;
}
__device__ __forceinline__ float bfLO(u32 v) {
    union { u32 u; float f; } x; x.u = v << 16; return x.f;
}
__device__ __forceinline__ float bfHI(u32 v) {
    union { u32 u; float f; } x; x.u = v & 0xffff0000u; return x.f;
}
__device__ __forceinline__ u32 sub2_pk(u32 t, u32 h) {
    return cvt_pk_bf16(bfLO(t) - bfLO(h), bfHI(t) - bfHI(h));
}
__device__ __forceinline__ u32 relu2_pk(float a, float b) {
    return cvt_pk_bf16(a > 0.f ? a : 0.f, b > 0.f ? b : 0.f);
}

union frag_cast { uint4 u; bf16x8 v; };

// ---------------- precompute kernels ----------------

__global__ void cvt_atom(const float* __restrict__ atom, u32* __restrict__ out) {
    int total = NN * ATU;
    for (int i = blockIdx.x * blockDim.x + threadIdx.x; i < total; i += gridDim.x * blockDim.x) {
        int n = i / ATU;
        int cu = i - n * ATU;
        int k = 2 * cu;
        float f0 = (k < AF) ? atom[n * AF + k] : 0.f;
        float f1 = (k + 1 < AF) ? atom[n * AF + k + 1] : 0.f;
        out[i] = pack2(f0, f1);
    }
}

__device__ __forceinline__ float wcol(const float* W, int n, int Kw, int len1, int off2, int len2, int k) {
    if (k < len1) return W[n * Kw + k];
    int j = k - off2;
    if (j >= 0 && j < len2) return W[n * Kw + len1 + j];
    return 0.f;
}
__global__ void cvt_w(const float* __restrict__ W, u32* __restrict__ out,
                      int Kw, int KpU, int len1, int off2, int len2) {
    int total = 128 * KpU;
    for (int i = blockIdx.x * blockDim.x + threadIdx.x; i < total; i += gridDim.x * blockDim.x) {
        int p = i / KpU;
        int cu = i - p * KpU;
        int t = p & 63;
        int c = (p & 64) + 2 * (t & 15) + ((t >> 4) & 1) + 32 * ((t >> 5) & 1);
        int k = 2 * cu;
        out[i] = pack2(wcol(W, c, Kw, len1, off2, len2, k),
                       wcol(W, c, Kw, len1, off2, len2, k + 1));
    }
}

// ---------------- CSR build ----------------

__global__ void hist(const int* __restrict__ dst, int* __restrict__ cnt) {
    for (int e = blockIdx.x * blockDim.x + threadIdx.x; e < NE; e += gridDim.x * blockDim.x)
        atomicAdd(&cnt[dst[e]], 1);
}

__global__ void scan1(const int* __restrict__ cnt, int* __restrict__ lexc, int* __restrict__ chunkSum) {
    __shared__ int s[256];
    int t = threadIdx.x, idx = blockIdx.x * 256 + t;
    int v = (idx < NN) ? cnt[idx] : 0;
    s[t] = v; __syncthreads();
    for (int off = 1; off < 256; off <<= 1) {
        int x = (t >= off) ? s[t - off] : 0;
        __syncthreads();
        s[t] += x;
        __syncthreads();
    }
    if (idx < NN) lexc[idx] = s[t] - v;
    if (t == 255) chunkSum[blockIdx.x] = s[255];
}

__global__ void scan2(const int* __restrict__ chunkSum, int* __restrict__ chunkOff) {
    __shared__ int s[256];
    int t = threadIdx.x;
    int v = (t < NCH) ? chunkSum[t] : 0;
    s[t] = v; __syncthreads();
    for (int off = 1; off < 256; off <<= 1) {
        int x = (t >= off) ? s[t - off] : 0;
        __syncthreads();
        s[t] += x;
        __syncthreads();
    }
    if (t < NCH) chunkOff[t] = s[t] - v;
}

__global__ void scan3(const int* __restrict__ lexc, const int* __restrict__ chunkOff,
                      int* __restrict__ rowptr, int* __restrict__ cursor) {
    int idx = blockIdx.x * 256 + threadIdx.x;
    if (idx < NN) {
        int v = lexc[idx] + chunkOff[blockIdx.x];
        rowptr[idx] = v;
        cursor[idx] = v;
    }
    if (idx == 0) rowptr[NN] = NE;
}

__global__ void scatter(const int* __restrict__ dst, const int* __restrict__ rev,
                        int* __restrict__ cursor, int* __restrict__ fidx,
                        int* __restrict__ sidx, int* __restrict__ posOf) {
    for (int e = blockIdx.x * blockDim.x + threadIdx.x; e < NE; e += gridDim.x * blockDim.x) {
        int d = dst[e];
        int pos = atomicAdd(&cursor[d], 1);
        fidx[pos] = rev[e];
        sidx[pos] = d;        // = src[fidx[pos]], nondecreasing over pos
        posOf[e] = pos;
    }
}

__global__ void pidx_build(const int* __restrict__ fidx, const int* __restrict__ posOf,
                           int* __restrict__ pidx) {
    for (int p = blockIdx.x * blockDim.x + threadIdx.x; p < NE; p += gridDim.x * blockDim.x)
        pidx[p] = posOf[fidx[p]];
}

// ---------------- streaming segment sum ----------------
// Wave owns pos-window [64w, 64w+64); computes FULL sums for nodes whose
// segment STARTS in the window (tail node extends past it). lane = u32 col;
// one load = one full 256-B h row. Node of slot i = sidx[i]; row = G ?
// pidx-broadcast : sequential. No atomics; every row read exactly once.
// tmp must be pre-zeroed once (zero-degree nodes never stored).
template<bool G>
__global__ __launch_bounds__(256)
void segsum_s(const int* __restrict__ sidx, const int* __restrict__ gat,
              const u32* __restrict__ h, u32* __restrict__ tmp)
{
    const int lane = threadIdx.x & 63;
    const int wid  = (blockIdx.x * 256 + threadIdx.x) >> 6;
    const int w0 = wid * 64;
    if (w0 >= NE) return;

    int nd = sidx[w0 + lane];
    int pd = G ? gat[w0 + lane] : 0;
    int cur = __shfl(nd, 0);
    int r = 0;
    if (w0 > 0 && sidx[w0 - 1] == cur) {
        // leading rows continue a node owned by an earlier wave: skip (no reads)
        while (r < 64 && __shfl(nd, r) == cur) ++r;
        if (r == 64) return;             // whole window mid-node
        cur = __shfl(nd, r);
    }
    float a0 = 0.f, a1 = 0.f;
    #pragma unroll 4
    for (; r < 64; ++r) {
        int nr = __shfl(nd, r);
        if (nr != cur) {
            tmp[(size_t)cur * 64 + lane] = cvt_pk_bf16(a0, a1);
            a0 = 0.f; a1 = 0.f; cur = nr;
        }
        int row = G ? __shfl(pd, r) : (w0 + r);
        u32 u = h[(size_t)row * 64 + lane];
        a0 += bfLO(u); a1 += bfHI(u);
    }
    // tail node may extend past the window: chunked continuation
    int p = w0 + 64;
    while (p < NE) {
        int idx = p + lane; if (idx > NE - 1) idx = NE - 1;
        int nd2 = sidx[idx];
        int pd2 = G ? gat[idx] : 0;
        const int lim = (p + 64 <= NE) ? 64 : (NE - p);
        int k = 0;
        for (; k < lim; ++k) {
            if (__shfl(nd2, k) != cur) break;
            int row = G ? __shfl(pd2, k) : (p + k);
            u32 u = h[(size_t)row * 64 + lane];
            a0 += bfLO(u); a1 += bfHI(u);
        }
        p += k;
        if (k < lim || lim < 64) break;
    }
    tmp[(size_t)cur * 64 + lane] = cvt_pk_bf16(a0, a1);
}

// ---------------- k_init: persistent waves, VMEM-free MFMA loop ----------------
__global__ __launch_bounds__(256, 3)
void k_init(const u32* __restrict__ atomBf, const float* __restrict__ bond,
            const int* __restrict__ fidx, const int* __restrict__ sidx,
            const int* __restrict__ pidx, const u32* __restrict__ Wp,
            u32* __restrict__ hout)
{
    __shared__ u32 Wlds[128 * 96];   // 49152 B; phys slot = slot ^ (row&7)
    const int tid  = threadIdx.x;
    const int lane = tid & 63;
    const int wv   = tid >> 6;
    const int ln   = lane & 15;
    const int q    = lane >> 4;

    {
        const int row = tid >> 1;        // 128 rows, 2 threads/row
        const int half = tid & 1;        // 10 slots of 16 B each
        const int rx = row & 7;
        #pragma unroll
        for (int sl = 0; sl < 10; ++sl) {
            int L = half * 10 + sl;      // 0..19
            int P = L ^ rx;              // <= 23, fits 24-slot stride
            *(uint4*)(Wlds + row * 96 + P * 4) = *(const uint4*)(Wp + row * KPU1 + L * 4);
        }
    }
    __syncthreads();

    const int NT = NE / 16;              // 50000 tiles of 16 rows
    const int stride = gridDim.x * 4;
    int s = blockIdx.x * 4 + wv;
    if (s >= NT) return;

    uint4  rA[4];
    uint4  rA4;
    float2 b01, b23, b45, b67;
    int4   stA;

    {
        int p = s * 16 + ln;
        int sr = sidx[p];
        int fr = fidx[p];
        stA = *(const int4*)(pidx + s * 16 + 4 * q);
        const u32* ab = atomBf + (size_t)sr * ATU;
        #pragma unroll
        for (int kc = 0; kc < 4; ++kc)
            rA[kc] = *(const uint4*)(ab + kc * 16 + q * 4);
        if (q == 0) rA4 = *(const uint4*)(ab + 64);
        const float* bp = bond + (size_t)fr * 14;
        if (q == 1) {
            b01 = *(const float2*)(bp + 0); b23 = *(const float2*)(bp + 2);
            b45 = *(const float2*)(bp + 4); b67 = *(const float2*)(bp + 6);
        } else if (q == 2) {
            b01 = *(const float2*)(bp + 8); b23 = *(const float2*)(bp + 10);
            b45 = *(const float2*)(bp + 12);
        }
    }

    while (true) {
        const int sn = s + stride;
        const bool more = sn < NT;       // wave-uniform

        int srB = 0, frB = 0;
        int4 stB;
        if (more) {
            int p = sn * 16 + ln;
            srB = sidx[p];
            frB = fidx[p];
            stB = *(const int4*)(pidx + sn * 16 + 4 * q);
        }

        bf16x8 aF[5];
        #pragma unroll
        for (int kc = 0; kc < 4; ++kc) { frag_cast fc; fc.u = rA[kc]; aF[kc] = fc.v; }
        {
            frag_cast f4;
            if (q == 0)      f4.u = rA4;
            else if (q == 1) f4.u = make_uint4(cvt_pk_bf16(b01.x, b01.y), cvt_pk_bf16(b23.x, b23.y),
                                               cvt_pk_bf16(b45.x, b45.y), cvt_pk_bf16(b67.x, b67.y));
            else if (q == 2) f4.u = make_uint4(cvt_pk_bf16(b01.x, b01.y), cvt_pk_bf16(b23.x, b23.y),
                                               cvt_pk_bf16(b45.x, b45.y), 0u);
            else             f4.u = make_uint4(0u, 0u, 0u, 0u);
            aF[4] = f4.v;
        }

        if (more) {
            const u32* ab = atomBf + (size_t)srB * ATU;
            #pragma unroll
            for (int kc = 0; kc < 4; ++kc)
                rA[kc] = *(const uint4*)(ab + kc * 16 + q * 4);
            if (q == 0) rA4 = *(const uint4*)(ab + 64);
            const float* bp = bond + (size_t)frB * 14;
            if (q == 1) {
                b01 = *(const float2*)(bp + 0); b23 = *(const float2*)(bp + 2);
                b45 = *(const float2*)(bp + 4); b67 = *(const float2*)(bp + 6);
            } else if (q == 2) {
                b01 = *(const float2*)(bp + 8); b23 = *(const float2*)(bp + 10);
                b45 = *(const float2*)(bp + 12);
            }
        }

        u32 zoff = 0;
        asm volatile("" : "+v"(zoff));   // defeat LICM: keep B ds_reads in-loop
        f32x4 acc[8] = {};
        #pragma unroll
        for (int kc = 0; kc < 5; ++kc) {
            const u32* wrow = Wlds + zoff + ln * 96 + (((kc * 4 + q) ^ (ln & 7)) << 2);
            #pragma unroll
            for (int j = 0; j < 8; ++j) {
                bf16x8 b = *(const bf16x8*)(wrow + j * 1536);   // +16 rows * 96 u32
                acc[j] = __builtin_amdgcn_mfma_f32_16x16x32_bf16(aF[kc], b, acc[j], 0, 0, 0);
            }
        }

        #pragma unroll
        for (int r = 0; r < 4; ++r) {
            int wrow = (r == 0) ? stA.x : (r == 1) ? stA.y : (r == 2) ? stA.z : stA.w;
            u32* orow = hout + (size_t)wrow * 64;
            #pragma unroll
            for (int a = 0; a < 4; ++a)
                orow[16 * a + ln] = relu2_pk(acc[2 * a][r], acc[2 * a + 1][r]);
        }

        if (!more) break;
        s = sn;
        stA = stB;
    }
}

// ---------------- k_msg: persistent waves, VMEM-free MFMA loop ----------------
template<bool USEIDX>
__global__ __launch_bounds__(256, 4)
void k_msg_t(const int* __restrict__ sidx, const int* __restrict__ pidx,
             const u32* __restrict__ Wp, const u32* __restrict__ tmp,
             u32* __restrict__ h)
{
    __shared__ u32 Wlds[128 * 64];   // 32 KB; slot phys = slot ^ (row&15)
    const int tid  = threadIdx.x;
    const int lane = tid & 63;
    const int wv   = tid >> 6;
    const int ln   = lane & 15;
    const int q    = lane >> 4;

    {
        const int row = tid >> 1;        // 128 rows, 2 threads/row
        const int half = tid & 1;        // 8 slots of 16 B each
        const int rx = row & 15;
        #pragma unroll
        for (int sl = 0; sl < 8; ++sl) {
            int L = half * 8 + sl;
            int P = L ^ rx;
            *(uint4*)(Wlds + row * 64 + P * 4) = *(const uint4*)(Wp + row * 64 + L * 4);
        }
    }
    __syncthreads();

    const int NT = NE / 16;              // 50000 tiles of 16 rows
    const int stride = gridDim.x * 4;
    int s = blockIdx.x * 4 + wv;
    if (s >= NT) return;

    int4  stA;
    uint4 tv[4], hv[4];

    {
        int p = s * 16 + ln;
        int sr = sidx[p];
        int hr = USEIDX ? pidx[p] : p;
        if (USEIDX) stA = *(const int4*)(pidx + s * 16 + 4 * q);
        const u32* tb = tmp + (size_t)sr * 64 + q * 4;
        const u32* hb = h   + (size_t)hr * 64 + q * 4;
        #pragma unroll
        for (int kc = 0; kc < 4; ++kc) {
            tv[kc] = *(const uint4*)(tb + kc * 16);
            hv[kc] = *(const uint4*)(hb + kc * 16);
        }
    }

    while (true) {
        const int sn = s + stride;
        const bool more = sn < NT;       // wave-uniform

        int srB = 0, hrB = 0;
        int4 stB;
        if (more) {
            int p = sn * 16 + ln;
            srB = sidx[p];
            hrB = USEIDX ? pidx[p] : p;
            if (USEIDX) stB = *(const int4*)(pidx + sn * 16 + 4 * q);
        }

        bf16x8 aF[4];
        #pragma unroll
        for (int kc = 0; kc < 4; ++kc) {
            frag_cast fc;
            fc.u.x = sub2_pk(tv[kc].x, hv[kc].x);
            fc.u.y = sub2_pk(tv[kc].y, hv[kc].y);
            fc.u.z = sub2_pk(tv[kc].z, hv[kc].z);
            fc.u.w = sub2_pk(tv[kc].w, hv[kc].w);
            aF[kc] = fc.v;
        }

        if (more) {
            const u32* tb = tmp + (size_t)srB * 64 + q * 4;
            const u32* hb = h   + (size_t)hrB * 64 + q * 4;
            #pragma unroll
            for (int kc = 0; kc < 4; ++kc) {
                tv[kc] = *(const uint4*)(tb + kc * 16);
                hv[kc] = *(const uint4*)(hb + kc * 16);
            }
        }

        u32 zoff = 0;
        asm volatile("" : "+v"(zoff));   // defeat LICM: keep B ds_reads in-loop
        f32x4 acc[8] = {};
        #pragma unroll
        for (int kc = 0; kc < 4; ++kc) {
            const u32* wrow = Wlds + zoff + ln * 64 + (((kc * 4 + q) ^ ln) << 2);
            #pragma unroll
            for (int j = 0; j < 8; ++j) {
                bf16x8 b = *(const bf16x8*)(wrow + j * 1024);
                acc[j] = __builtin_amdgcn_mfma_f32_16x16x32_bf16(aF[kc], b, acc[j], 0, 0, 0);
            }
        }

        #pragma unroll
        for (int r = 0; r < 4; ++r) {
            int wrow = USEIDX
                ? ((r == 0) ? stA.x : (r == 1) ? stA.y : (r == 2) ? stA.z : stA.w)
                : (s * 16 + 4 * q + r);
            u32* orow = h + (size_t)wrow * 64;
            #pragma unroll
            for (int a = 0; a < 4; ++a)
                orow[16 * a + ln] = relu2_pk(acc[2 * a][r], acc[2 * a + 1][r]);
        }

        if (!more) break;
        s = sn;
        if (USEIDX) stA = stB;
    }
}

// ---------------- k_out: persistent 16-node tiles, VMEM-free MFMA loop ----------------
__global__ __launch_bounds__(256, 2)
void k_out_p(const u32* __restrict__ atomBf, const u32* __restrict__ Wp,
             const u32* __restrict__ tmp, float* __restrict__ out)
{
    __shared__ u32 Wlds[128 * KPU3];   // 75776 B -> 2 blocks/CU
    const int tid  = threadIdx.x;
    const int lane = tid & 63;
    const int wv   = tid >> 6;
    const int ln   = lane & 15;
    const int q    = lane >> 4;

    {
        const int row = tid >> 1;        // 128 rows, 2 threads/row
        const int half = tid & 1;        // 18 slots of 16 B each
        #pragma unroll
        for (int sl = 0; sl < 18; ++sl) {
            int L = half * 18 + sl;      // 0..35
            *(uint4*)(Wlds + row * KPU3 + L * 4) = *(const uint4*)(Wp + row * KPU3 + L * 4);
        }
    }
    __syncthreads();

    const int NT = NN / 16;              // 3125 tiles of 16 nodes
    const int stride = gridDim.x * 4;
    int s = blockIdx.x * 4 + wv;
    if (s >= NT) return;

    uint4 rA[9];
    auto gather = [&](int ss, uint4* r) {
        int n = ss * 16 + ln;
        const u32* ab = atomBf + (size_t)n * ATU;
        const u32* tp = tmp + (size_t)n * 64;
        #pragma unroll
        for (int kc = 0; kc < 4; ++kc)
            r[kc] = *(const uint4*)(ab + kc * 16 + q * 4);
        if (q == 0) {
            r[4] = *(const uint4*)(ab + 64);
            r[5] = *(const uint4*)(tp + 12);
            r[6] = *(const uint4*)(tp + 28);
            r[7] = *(const uint4*)(tp + 44);
            r[8] = *(const uint4*)(tp + 60);
        } else {
            r[4] = *(const uint4*)(tp + (q - 1) * 4);
            r[5] = *(const uint4*)(tp + 12 + q * 4);
            r[6] = *(const uint4*)(tp + 28 + q * 4);
            r[7] = *(const uint4*)(tp + 44 + q * 4);
            r[8] = make_uint4(0u, 0u, 0u, 0u);
        }
    };

    gather(s, rA);

    while (true) {
        const int sn = s + stride;
        const bool more = sn < NT;       // wave-uniform

        bf16x8 aF[9];
        #pragma unroll
        for (int kc = 0; kc < 9; ++kc) { frag_cast fc; fc.u = rA[kc]; aF[kc] = fc.v; }

        if (more) gather(sn, rA);        // prefetch rides through MFMA (LDS B)

        u32 zoff = 0;
        asm volatile("" : "+v"(zoff));   // defeat LICM: keep B ds_reads in-loop
        f32x4 acc[8] = {};
        #pragma unroll
        for (int kc = 0; kc < KC3; ++kc) {
            const u32* wrow = Wlds + zoff + ln * KPU3 + (kc * 4 + q) * 4;
            #pragma unroll
            for (int j = 0; j < 8; ++j) {
                bf16x8 b = *(const bf16x8*)(wrow + j * (16 * KPU3));
                acc[j] = __builtin_amdgcn_mfma_f32_16x16x32_bf16(aF[kc], b, acc[j], 0, 0, 0);
            }
        }

        // store: 16 nodes x 128 f32; channel(a, ln) = 32a + 2ln (+1)
        #pragma unroll
        for (int r = 0; r < 4; ++r) {
            int n = s * 16 + 4 * q + r;
            float2* orow = (float2*)(out + (size_t)n * HID);
            #pragma unroll
            for (int a = 0; a < 4; ++a) {
                float2 v;
                v.x = relu(acc[2 * a][r]);
                v.y = relu(acc[2 * a + 1][r]);
                orow[16 * a + ln] = v;
            }
        }

        if (!more) break;
        s = sn;
    }
}

// ---------------- launch ----------------

extern "C" void kernel_launch(void* const* d_in, const int* in_sizes, int n_in,
                              void* d_out, int out_size, void* d_ws, size_t ws_size,
                              hipStream_t stream) {
    const float* atom = (const float*)d_in[0];   // [50000][133]
    const float* bond = (const float*)d_in[1];   // [800000][14]
    const float* Wi   = (const float*)d_in[2];   // [128][147]
    const float* Wh   = (const float*)d_in[3];   // [128][128]
    const float* Wo   = (const float*)d_in[4];   // [128][261]
    const int*   src  = (const int*)d_in[5]; (void)src;
    const int*   dst  = (const int*)d_in[6];
    const int*   rev  = (const int*)d_in[7];
    float* out = (float*)d_out;

    char* ws = (char*)d_ws;
    size_t off = 0;
    auto take = [&](size_t bytes) { char* p = ws + off; off = (off + bytes + 255) & ~(size_t)255; return p; };
    u32* hbuf   = (u32*)take((size_t)NE * 64 * 4);     // 204.8 MB
    u32* tmp    = (u32*)take((size_t)NN * 64 * 4);     // 12.8 MB
    u32* atomBf = (u32*)take((size_t)NN * ATU * 4);    // 13.6 MB
    int* fidx   = (int*)take((size_t)NE * 4);
    int* sidx   = (int*)take((size_t)NE * 4);
    int* posOf  = (int*)take((size_t)NE * 4);
    int* pidx   = (int*)take((size_t)NE * 4);
    int* cnt    = (int*)take((size_t)NN * 4);
    int* lexc   = (int*)take((size_t)NN * 4);
    int* rowptr = (int*)take((size_t)(NN + 1) * 4);
    int* cursor = (int*)take((size_t)NN * 4);
    int* chunkSum = (int*)take(256 * 4);
    int* chunkOff = (int*)take(256 * 4);
    u32* WiP = (u32*)take(128 * KPU1 * 4);
    u32* WhP = (u32*)take(128 * WHU * 4);
    u32* WoP = (u32*)take(128 * KPU3 * 4);
    // total ~245 MB (round-14 proven footprint)

    cvt_atom<<<2048, 256, 0, stream>>>(atom, atomBf);
    cvt_w<<<48, 256, 0, stream>>>(Wi, WiP, 147, KPU1, 133, 136, 14);
    cvt_w<<<32, 256, 0, stream>>>(Wh, WhP, 128, WHU, 128, 1 << 20, 0);
    cvt_w<<<80, 256, 0, stream>>>(Wo, WoP, 261, KPU3, 133, 136, 128);

    hipMemsetAsync(cnt, 0, (size_t)NN * 4, stream);
    hipMemsetAsync(tmp, 0, (size_t)NN * 64 * 4, stream);   // zero-degree-node safety
    hist<<<1024, 256, 0, stream>>>(dst, cnt);
    scan1<<<NCH, 256, 0, stream>>>(cnt, lexc, chunkSum);
    scan2<<<1, 256, 0, stream>>>(chunkSum, chunkOff);
    scan3<<<NCH, 256, 0, stream>>>(lexc, chunkOff, rowptr, cursor);
    scatter<<<1024, 256, 0, stream>>>(dst, rev, cursor, fidx, sidx, posOf);
    pidx_build<<<1024, 256, 0, stream>>>(fidx, posOf, pidx);

    k_init<<<768, 256, 0, stream>>>(atomBf, bond, fidx, sidx, pidx, WiP, hbuf);   // e-layout
    segsum_s<false><<<3125, 256, 0, stream>>>(sidx, nullptr, hbuf, tmp);          // streaming seq
    k_msg_t<false><<<1024, 256, 0, stream>>>(sidx, pidx, WhP, tmp, hbuf);         // all-stream -> f-layout
    segsum_s<true><<<3125, 256, 0, stream>>>(sidx, pidx, hbuf, tmp);              // streaming gather
    k_msg_t<true><<<1024, 256, 0, stream>>>(sidx, pidx, WhP, tmp, hbuf);          // random rows -> e-layout
    segsum_s<false><<<3125, 256, 0, stream>>>(sidx, nullptr, hbuf, tmp);          // streaming seq
    k_out_p<<<512, 256, 0, stream>>>(atomBf, WoP, tmp, out);
}

// Round 11
// 612.957 us; speedup vs baseline: 1.1246x; 1.1246x over previous
//
#include <hip/hip_runtime.h>

// DMPNN encoder, MI355X bf16-MFMA, round 17: segsum_s v2 — preload-then-scan.
//
// r16's streaming segsum was semantically right (passed) but issue-rate wrong
// (102us, 1.16 TB/s, VALU 16%): one 4B/lane load per iteration interleaved
// with dependent shfl + conditional store -> no load batching, serial vmcnt
// waits. v2 phase-splits the wave: (1) preload all 64 row-columns into 64
// VGPRs (independent, issued back-to-back -> ~64 outstanding loads), (2)
// fully-unrolled register scan (static indices; leading-skip via ballot+ctz),
// (3) rare tail continuation chunked as before. Ownership semantics identical
// to r16: wave owns segments starting in its 64-row window; tail node extends
// past it; no atomics; tmp pre-zeroed once for zero-degree nodes.
//
// Pipeline (pos-space, alternating e-/f-layout; identities:
//   fidx[p]=rev[eidx[p]], sidx[p]=dst[eidx[p]] (sorted),
//   pidx[p]=posOf[fidx[p]] fix-point-free involution):
//   k_init : persistent waves, Wi in LDS (96-stride 24-slot XOR), e-layout @pidx[p]
//   segsum1: segsum_s<false> (e-layout rows sequential)
//   k_msg1 : tmp[sidx[p]] - h0@p -> h1 f-layout @p
//   segsum2: segsum_s<true>  (rows pidx[i], node sidx[i])
//   k_msg2 : tmp[sidx[p]] - h1@pidx[p] -> h2 e-layout @pidx[p]
//   segsum3: segsum_s<false>
//   k_out  : persistent 16-node tiles (r14 form)
//
// Weight channel permutation c(p) = (p&64) + 2*(p&15) + ((p>>4)&1) + 32*((p>>5)&1):
// acc pair (2a,2a+1) at lane ln = channels 32a+2ln, 32a+2ln+1; u32 col u holds
// channels 2u,2u+1 (natural order).

typedef unsigned int u32;
typedef unsigned short u16;
typedef unsigned long long u64;
using bf16x8 = __attribute__((ext_vector_type(8))) __bf16;
using f32x4  = __attribute__((ext_vector_type(4))) float;

#define NN 50000
#define NP 400000
#define NE 800000
#define AF 133
#define HID 128
#define ATU 68      // atomBf row stride in u32
#define KPU1 80     // Wi packed row stride in u32 (160 cols = 5 kc chunks)
#define WHU 64      // Wh packed row stride (u32) = 256 B rows
#define KPU3 148    // Wo packed row stride; 144 data u32 = 288 cols = 9 chunks
#define KC3 9
#define NCH 196     // scan chunks of 256 covering NN

__device__ __forceinline__ u16 f2bf(float f) {
    union { float f; u32 u; } x; x.f = f;
    u32 r = x.u + 0x7fffu + ((x.u >> 16) & 1u);   // RNE
    return (u16)(r >> 16);
}
__device__ __forceinline__ float bf2f(u16 b) {
    union { u32 u; float f; } x; x.u = ((u32)b) << 16;
    return x.f;
}
__device__ __forceinline__ float lo16(u32 v) { return bf2f((u16)v); }
__device__ __forceinline__ float hi16(u32 v) { return bf2f((u16)(v >> 16)); }
__device__ __forceinline__ u32 pack2(float a, float b) {
    return (u32)f2bf(a) | ((u32)f2bf(b) << 16);
}
__device__ __forceinline__ float relu(float v) { return v > 0.f ? v : 0.f; }

// single-instruction RNE pack of two f32 -> packed bf16x2 (no builtin on gfx950)
__device__ __forceinline__ u32 cvt_pk_bf16(float lo, float hi) {
    u32 r;
    asm("v_cvt_pk_bf16_f32 %0, %1, %2" : "=v"(r) : "v"(lo), "v"(hi));
    return r;
}
__device__ __forceinline__ float bfLO(u32 v) {
    union { u32 u; float f; } x; x.u = v << 16; return x.f;
}
__device__ __forceinline__ float bfHI(u32 v) {
    union { u32 u; float f; } x; x.u = v & 0xffff0000u; return x.f;
}
__device__ __forceinline__ u32 sub2_pk(u32 t, u32 h) {
    return cvt_pk_bf16(bfLO(t) - bfLO(h), bfHI(t) - bfHI(h));
}
__device__ __forceinline__ u32 relu2_pk(float a, float b) {
    return cvt_pk_bf16(a > 0.f ? a : 0.f, b > 0.f ? b : 0.f);
}

union frag_cast { uint4 u; bf16x8 v; };

// ---------------- precompute kernels ----------------

__global__ void cvt_atom(const float* __restrict__ atom, u32* __restrict__ out) {
    int total = NN * ATU;
    for (int i = blockIdx.x * blockDim.x + threadIdx.x; i < total; i += gridDim.x * blockDim.x) {
        int n = i / ATU;
        int cu = i - n * ATU;
        int k = 2 * cu;
        float f0 = (k < AF) ? atom[n * AF + k] : 0.f;
        float f1 = (k + 1 < AF) ? atom[n * AF + k + 1] : 0.f;
        out[i] = pack2(f0, f1);
    }
}

__device__ __forceinline__ float wcol(const float* W, int n, int Kw, int len1, int off2, int len2, int k) {
    if (k < len1) return W[n * Kw + k];
    int j = k - off2;
    if (j >= 0 && j < len2) return W[n * Kw + len1 + j];
    return 0.f;
}
__global__ void cvt_w(const float* __restrict__ W, u32* __restrict__ out,
                      int Kw, int KpU, int len1, int off2, int len2) {
    int total = 128 * KpU;
    for (int i = blockIdx.x * blockDim.x + threadIdx.x; i < total; i += gridDim.x * blockDim.x) {
        int p = i / KpU;
        int cu = i - p * KpU;
        int t = p & 63;
        int c = (p & 64) + 2 * (t & 15) + ((t >> 4) & 1) + 32 * ((t >> 5) & 1);
        int k = 2 * cu;
        out[i] = pack2(wcol(W, c, Kw, len1, off2, len2, k),
                       wcol(W, c, Kw, len1, off2, len2, k + 1));
    }
}

// ---------------- CSR build ----------------

__global__ void hist(const int* __restrict__ dst, int* __restrict__ cnt) {
    for (int e = blockIdx.x * blockDim.x + threadIdx.x; e < NE; e += gridDim.x * blockDim.x)
        atomicAdd(&cnt[dst[e]], 1);
}

__global__ void scan1(const int* __restrict__ cnt, int* __restrict__ lexc, int* __restrict__ chunkSum) {
    __shared__ int s[256];
    int t = threadIdx.x, idx = blockIdx.x * 256 + t;
    int v = (idx < NN) ? cnt[idx] : 0;
    s[t] = v; __syncthreads();
    for (int off = 1; off < 256; off <<= 1) {
        int x = (t >= off) ? s[t - off] : 0;
        __syncthreads();
        s[t] += x;
        __syncthreads();
    }
    if (idx < NN) lexc[idx] = s[t] - v;
    if (t == 255) chunkSum[blockIdx.x] = s[255];
}

__global__ void scan2(const int* __restrict__ chunkSum, int* __restrict__ chunkOff) {
    __shared__ int s[256];
    int t = threadIdx.x;
    int v = (t < NCH) ? chunkSum[t] : 0;
    s[t] = v; __syncthreads();
    for (int off = 1; off < 256; off <<= 1) {
        int x = (t >= off) ? s[t - off] : 0;
        __syncthreads();
        s[t] += x;
        __syncthreads();
    }
    if (t < NCH) chunkOff[t] = s[t] - v;
}

__global__ void scan3(const int* __restrict__ lexc, const int* __restrict__ chunkOff,
                      int* __restrict__ rowptr, int* __restrict__ cursor) {
    int idx = blockIdx.x * 256 + threadIdx.x;
    if (idx < NN) {
        int v = lexc[idx] + chunkOff[blockIdx.x];
        rowptr[idx] = v;
        cursor[idx] = v;
    }
    if (idx == 0) rowptr[NN] = NE;
}

__global__ void scatter(const int* __restrict__ dst, const int* __restrict__ rev,
                        int* __restrict__ cursor, int* __restrict__ fidx,
                        int* __restrict__ sidx, int* __restrict__ posOf) {
    for (int e = blockIdx.x * blockDim.x + threadIdx.x; e < NE; e += gridDim.x * blockDim.x) {
        int d = dst[e];
        int pos = atomicAdd(&cursor[d], 1);
        fidx[pos] = rev[e];
        sidx[pos] = d;        // = src[fidx[pos]], nondecreasing over pos
        posOf[e] = pos;
    }
}

__global__ void pidx_build(const int* __restrict__ fidx, const int* __restrict__ posOf,
                           int* __restrict__ pidx) {
    for (int p = blockIdx.x * blockDim.x + threadIdx.x; p < NE; p += gridDim.x * blockDim.x)
        pidx[p] = posOf[fidx[p]];
}

// ---------------- streaming segment sum v2: preload-then-scan ----------------
// Wave owns pos-window [64w, 64w+64); computes FULL sums for nodes whose
// segment STARTS in the window. lane = u32 col; one load = one 256-B h row.
// Phase 1: all 64 row-columns -> 64 VGPRs (independent loads, max MLP).
// Phase 2: fully-unrolled register scan; leading-skip via ballot+ctz.
// Phase 3: tail node continuation past the window (chunked, rare).
// No atomics; every h row read exactly once; tmp pre-zeroed once.
template<bool G>
__global__ __launch_bounds__(256)
void segsum_s(const int* __restrict__ sidx, const int* __restrict__ gat,
              const u32* __restrict__ h, u32* __restrict__ tmp)
{
    const int lane = threadIdx.x & 63;
    const int wid  = (blockIdx.x * 256 + threadIdx.x) >> 6;
    const int w0 = wid * 64;
    if (w0 >= NE) return;

    int nd = sidx[w0 + lane];
    int pd = G ? gat[w0 + lane] : 0;

    // ---- phase 1: preload all 64 rows into registers (max loads in flight)
    u32 v[64];
    #pragma unroll
    for (int r = 0; r < 64; ++r) {
        int row = G ? __shfl(pd, r) : (w0 + r);
        v[r] = h[(size_t)row * 64 + lane];
    }

    // ---- leading-skip: lanes continuing the previous wave's node (prefix)
    int start = 0;
    if (w0 > 0) {
        int prev = sidx[w0 - 1];
        u64 m = __ballot(nd == prev);
        if (~m == 0ull) return;          // whole window mid-node, not owned
        start = (int)__builtin_ctzll(~m);
    }
    int cur = __shfl(nd, start);

    // ---- phase 2: register scan (fully unrolled, static indices)
    float a0 = 0.f, a1 = 0.f;
    #pragma unroll
    for (int r = 0; r < 64; ++r) {
        if (r >= start) {
            int nr = __shfl(nd, r);
            if (nr != cur) {
                tmp[(size_t)cur * 64 + lane] = cvt_pk_bf16(a0, a1);
                a0 = 0.f; a1 = 0.f; cur = nr;
            }
            a0 += bfLO(v[r]); a1 += bfHI(v[r]);
        }
    }

    // ---- phase 3: tail node may extend past the window (chunked)
    int p = w0 + 64;
    while (p < NE) {
        int idx = p + lane; if (idx > NE - 1) idx = NE - 1;
        int nd2 = sidx[idx];
        int pd2 = G ? gat[idx] : 0;
        const int lim = (p + 64 <= NE) ? 64 : (NE - p);
        int k = 0;
        for (; k < lim; ++k) {
            if (__shfl(nd2, k) != cur) break;
            int row = G ? __shfl(pd2, k) : (p + k);
            u32 u = h[(size_t)row * 64 + lane];
            a0 += bfLO(u); a1 += bfHI(u);
        }
        p += k;
        if (k < lim || lim < 64) break;
    }
    tmp[(size_t)cur * 64 + lane] = cvt_pk_bf16(a0, a1);
}

// ---------------- k_init: persistent waves, VMEM-free MFMA loop ----------------
__global__ __launch_bounds__(256, 3)
void k_init(const u32* __restrict__ atomBf, const float* __restrict__ bond,
            const int* __restrict__ fidx, const int* __restrict__ sidx,
            const int* __restrict__ pidx, const u32* __restrict__ Wp,
            u32* __restrict__ hout)
{
    __shared__ u32 Wlds[128 * 96];   // 49152 B; phys slot = slot ^ (row&7)
    const int tid  = threadIdx.x;
    const int lane = tid & 63;
    const int wv   = tid >> 6;
    const int ln   = lane & 15;
    const int q    = lane >> 4;

    {
        const int row = tid >> 1;        // 128 rows, 2 threads/row
        const int half = tid & 1;        // 10 slots of 16 B each
        const int rx = row & 7;
        #pragma unroll
        for (int sl = 0; sl < 10; ++sl) {
            int L = half * 10 + sl;      // 0..19
            int P = L ^ rx;              // <= 23, fits 24-slot stride
            *(uint4*)(Wlds + row * 96 + P * 4) = *(const uint4*)(Wp + row * KPU1 + L * 4);
        }
    }
    __syncthreads();

    const int NT = NE / 16;              // 50000 tiles of 16 rows
    const int stride = gridDim.x * 4;
    int s = blockIdx.x * 4 + wv;
    if (s >= NT) return;

    uint4  rA[4];
    uint4  rA4;
    float2 b01, b23, b45, b67;
    int4   stA;

    {
        int p = s * 16 + ln;
        int sr = sidx[p];
        int fr = fidx[p];
        stA = *(const int4*)(pidx + s * 16 + 4 * q);
        const u32* ab = atomBf + (size_t)sr * ATU;
        #pragma unroll
        for (int kc = 0; kc < 4; ++kc)
            rA[kc] = *(const uint4*)(ab + kc * 16 + q * 4);
        if (q == 0) rA4 = *(const uint4*)(ab + 64);
        const float* bp = bond + (size_t)fr * 14;
        if (q == 1) {
            b01 = *(const float2*)(bp + 0); b23 = *(const float2*)(bp + 2);
            b45 = *(const float2*)(bp + 4); b67 = *(const float2*)(bp + 6);
        } else if (q == 2) {
            b01 = *(const float2*)(bp + 8); b23 = *(const float2*)(bp + 10);
            b45 = *(const float2*)(bp + 12);
        }
    }

    while (true) {
        const int sn = s + stride;
        const bool more = sn < NT;       // wave-uniform

        int srB = 0, frB = 0;
        int4 stB;
        if (more) {
            int p = sn * 16 + ln;
            srB = sidx[p];
            frB = fidx[p];
            stB = *(const int4*)(pidx + sn * 16 + 4 * q);
        }

        bf16x8 aF[5];
        #pragma unroll
        for (int kc = 0; kc < 4; ++kc) { frag_cast fc; fc.u = rA[kc]; aF[kc] = fc.v; }
        {
            frag_cast f4;
            if (q == 0)      f4.u = rA4;
            else if (q == 1) f4.u = make_uint4(cvt_pk_bf16(b01.x, b01.y), cvt_pk_bf16(b23.x, b23.y),
                                               cvt_pk_bf16(b45.x, b45.y), cvt_pk_bf16(b67.x, b67.y));
            else if (q == 2) f4.u = make_uint4(cvt_pk_bf16(b01.x, b01.y), cvt_pk_bf16(b23.x, b23.y),
                                               cvt_pk_bf16(b45.x, b45.y), 0u);
            else             f4.u = make_uint4(0u, 0u, 0u, 0u);
            aF[4] = f4.v;
        }

        if (more) {
            const u32* ab = atomBf + (size_t)srB * ATU;
            #pragma unroll
            for (int kc = 0; kc < 4; ++kc)
                rA[kc] = *(const uint4*)(ab + kc * 16 + q * 4);
            if (q == 0) rA4 = *(const uint4*)(ab + 64);
            const float* bp = bond + (size_t)frB * 14;
            if (q == 1) {
                b01 = *(const float2*)(bp + 0); b23 = *(const float2*)(bp + 2);
                b45 = *(const float2*)(bp + 4); b67 = *(const float2*)(bp + 6);
            } else if (q == 2) {
                b01 = *(const float2*)(bp + 8); b23 = *(const float2*)(bp + 10);
                b45 = *(const float2*)(bp + 12);
            }
        }

        u32 zoff = 0;
        asm volatile("" : "+v"(zoff));   // defeat LICM: keep B ds_reads in-loop
        f32x4 acc[8] = {};
        #pragma unroll
        for (int kc = 0; kc < 5; ++kc) {
            const u32* wrow = Wlds + zoff + ln * 96 + (((kc * 4 + q) ^ (ln & 7)) << 2);
            #pragma unroll
            for (int j = 0; j < 8; ++j) {
                bf16x8 b = *(const bf16x8*)(wrow + j * 1536);   // +16 rows * 96 u32
                acc[j] = __builtin_amdgcn_mfma_f32_16x16x32_bf16(aF[kc], b, acc[j], 0, 0, 0);
            }
        }

        #pragma unroll
        for (int r = 0; r < 4; ++r) {
            int wrow = (r == 0) ? stA.x : (r == 1) ? stA.y : (r == 2) ? stA.z : stA.w;
            u32* orow = hout + (size_t)wrow * 64;
            #pragma unroll
            for (int a = 0; a < 4; ++a)
                orow[16 * a + ln] = relu2_pk(acc[2 * a][r], acc[2 * a + 1][r]);
        }

        if (!more) break;
        s = sn;
        stA = stB;
    }
}

// ---------------- k_msg: persistent waves, VMEM-free MFMA loop ----------------
template<bool USEIDX>
__global__ __launch_bounds__(256, 4)
void k_msg_t(const int* __restrict__ sidx, const int* __restrict__ pidx,
             const u32* __restrict__ Wp, const u32* __restrict__ tmp,
             u32* __restrict__ h)
{
    __shared__ u32 Wlds[128 * 64];   // 32 KB; slot phys = slot ^ (row&15)
    const int tid  = threadIdx.x;
    const int lane = tid & 63;
    const int wv   = tid >> 6;
    const int ln   = lane & 15;
    const int q    = lane >> 4;

    {
        const int row = tid >> 1;        // 128 rows, 2 threads/row
        const int half = tid & 1;        // 8 slots of 16 B each
        const int rx = row & 15;
        #pragma unroll
        for (int sl = 0; sl < 8; ++sl) {
            int L = half * 8 + sl;
            int P = L ^ rx;
            *(uint4*)(Wlds + row * 64 + P * 4) = *(const uint4*)(Wp + row * 64 + L * 4);
        }
    }
    __syncthreads();

    const int NT = NE / 16;              // 50000 tiles of 16 rows
    const int stride = gridDim.x * 4;
    int s = blockIdx.x * 4 + wv;
    if (s >= NT) return;

    int4  stA;
    uint4 tv[4], hv[4];

    {
        int p = s * 16 + ln;
        int sr = sidx[p];
        int hr = USEIDX ? pidx[p] : p;
        if (USEIDX) stA = *(const int4*)(pidx + s * 16 + 4 * q);
        const u32* tb = tmp + (size_t)sr * 64 + q * 4;
        const u32* hb = h   + (size_t)hr * 64 + q * 4;
        #pragma unroll
        for (int kc = 0; kc < 4; ++kc) {
            tv[kc] = *(const uint4*)(tb + kc * 16);
            hv[kc] = *(const uint4*)(hb + kc * 16);
        }
    }

    while (true) {
        const int sn = s + stride;
        const bool more = sn < NT;       // wave-uniform

        int srB = 0, hrB = 0;
        int4 stB;
        if (more) {
            int p = sn * 16 + ln;
            srB = sidx[p];
            hrB = USEIDX ? pidx[p] : p;
            if (USEIDX) stB = *(const int4*)(pidx + sn * 16 + 4 * q);
        }

        bf16x8 aF[4];
        #pragma unroll
        for (int kc = 0; kc < 4; ++kc) {
            frag_cast fc;
            fc.u.x = sub2_pk(tv[kc].x, hv[kc].x);
            fc.u.y = sub2_pk(tv[kc].y, hv[kc].y);
            fc.u.z = sub2_pk(tv[kc].z, hv[kc].z);
            fc.u.w = sub2_pk(tv[kc].w, hv[kc].w);
            aF[kc] = fc.v;
        }

        if (more) {
            const u32* tb = tmp + (size_t)srB * 64 + q * 4;
            const u32* hb = h   + (size_t)hrB * 64 + q * 4;
            #pragma unroll
            for (int kc = 0; kc < 4; ++kc) {
                tv[kc] = *(const uint4*)(tb + kc * 16);
                hv[kc] = *(const uint4*)(hb + kc * 16);
            }
        }

        u32 zoff = 0;
        asm volatile("" : "+v"(zoff));   // defeat LICM: keep B ds_reads in-loop
        f32x4 acc[8] = {};
        #pragma unroll
        for (int kc = 0; kc < 4; ++kc) {
            const u32* wrow = Wlds + zoff + ln * 64 + (((kc * 4 + q) ^ ln) << 2);
            #pragma unroll
            for (int j = 0; j < 8; ++j) {
                bf16x8 b = *(const bf16x8*)(wrow + j * 1024);
                acc[j] = __builtin_amdgcn_mfma_f32_16x16x32_bf16(aF[kc], b, acc[j], 0, 0, 0);
            }
        }

        #pragma unroll
        for (int r = 0; r < 4; ++r) {
            int wrow = USEIDX
                ? ((r == 0) ? stA.x : (r == 1) ? stA.y : (r == 2) ? stA.z : stA.w)
                : (s * 16 + 4 * q + r);
            u32* orow = h + (size_t)wrow * 64;
            #pragma unroll
            for (int a = 0; a < 4; ++a)
                orow[16 * a + ln] = relu2_pk(acc[2 * a][r], acc[2 * a + 1][r]);
        }

        if (!more) break;
        s = sn;
        if (USEIDX) stA = stB;
    }
}

// ---------------- k_out: persistent 16-node tiles, VMEM-free MFMA loop ----------------
__global__ __launch_bounds__(256, 2)
void k_out_p(const u32* __restrict__ atomBf, const u32* __restrict__ Wp,
             const u32* __restrict__ tmp, float* __restrict__ out)
{
    __shared__ u32 Wlds[128 * KPU3];   // 75776 B -> 2 blocks/CU
    const int tid  = threadIdx.x;
    const int lane = tid & 63;
    const int wv   = tid >> 6;
    const int ln   = lane & 15;
    const int q    = lane >> 4;

    {
        const int row = tid >> 1;        // 128 rows, 2 threads/row
        const int half = tid & 1;        // 18 slots of 16 B each
        #pragma unroll
        for (int sl = 0; sl < 18; ++sl) {
            int L = half * 18 + sl;      // 0..35
            *(uint4*)(Wlds + row * KPU3 + L * 4) = *(const uint4*)(Wp + row * KPU3 + L * 4);
        }
    }
    __syncthreads();

    const int NT = NN / 16;              // 3125 tiles of 16 nodes
    const int stride = gridDim.x * 4;
    int s = blockIdx.x * 4 + wv;
    if (s >= NT) return;

    uint4 rA[9];
    auto gather = [&](int ss, uint4* r) {
        int n = ss * 16 + ln;
        const u32* ab = atomBf + (size_t)n * ATU;
        const u32* tp = tmp + (size_t)n * 64;
        #pragma unroll
        for (int kc = 0; kc < 4; ++kc)
            r[kc] = *(const uint4*)(ab + kc * 16 + q * 4);
        if (q == 0) {
            r[4] = *(const uint4*)(ab + 64);
            r[5] = *(const uint4*)(tp + 12);
            r[6] = *(const uint4*)(tp + 28);
            r[7] = *(const uint4*)(tp + 44);
            r[8] = *(const uint4*)(tp + 60);
        } else {
            r[4] = *(const uint4*)(tp + (q - 1) * 4);
            r[5] = *(const uint4*)(tp + 12 + q * 4);
            r[6] = *(const uint4*)(tp + 28 + q * 4);
            r[7] = *(const uint4*)(tp + 44 + q * 4);
            r[8] = make_uint4(0u, 0u, 0u, 0u);
        }
    };

    gather(s, rA);

    while (true) {
        const int sn = s + stride;
        const bool more = sn < NT;       // wave-uniform

        bf16x8 aF[9];
        #pragma unroll
        for (int kc = 0; kc < 9; ++kc) { frag_cast fc; fc.u = rA[kc]; aF[kc] = fc.v; }

        if (more) gather(sn, rA);        // prefetch rides through MFMA (LDS B)

        u32 zoff = 0;
        asm volatile("" : "+v"(zoff));   // defeat LICM: keep B ds_reads in-loop
        f32x4 acc[8] = {};
        #pragma unroll
        for (int kc = 0; kc < KC3; ++kc) {
            const u32* wrow = Wlds + zoff + ln * KPU3 + (kc * 4 + q) * 4;
            #pragma unroll
            for (int j = 0; j < 8; ++j) {
                bf16x8 b = *(const bf16x8*)(wrow + j * (16 * KPU3));
                acc[j] = __builtin_amdgcn_mfma_f32_16x16x32_bf16(aF[kc], b, acc[j], 0, 0, 0);
            }
        }

        // store: 16 nodes x 128 f32; channel(a, ln) = 32a + 2ln (+1)
        #pragma unroll
        for (int r = 0; r < 4; ++r) {
            int n = s * 16 + 4 * q + r;
            float2* orow = (float2*)(out + (size_t)n * HID);
            #pragma unroll
            for (int a = 0; a < 4; ++a) {
                float2 v;
                v.x = relu(acc[2 * a][r]);
                v.y = relu(acc[2 * a + 1][r]);
                orow[16 * a + ln] = v;
            }
        }

        if (!more) break;
        s = sn;
    }
}

// ---------------- launch ----------------

extern "C" void kernel_launch(void* const* d_in, const int* in_sizes, int n_in,
                              void* d_out, int out_size, void* d_ws, size_t ws_size,
                              hipStream_t stream) {
    const float* atom = (const float*)d_in[0];   // [50000][133]
    const float* bond = (const float*)d_in[1];   // [800000][14]
    const float* Wi   = (const float*)d_in[2];   // [128][147]
    const float* Wh   = (const float*)d_in[3];   // [128][128]
    const float* Wo   = (const float*)d_in[4];   // [128][261]
    const int*   src  = (const int*)d_in[5]; (void)src;
    const int*   dst  = (const int*)d_in[6];
    const int*   rev  = (const int*)d_in[7];
    float* out = (float*)d_out;

    char* ws = (char*)d_ws;
    size_t off = 0;
    auto take = [&](size_t bytes) { char* p = ws + off; off = (off + bytes + 255) & ~(size_t)255; return p; };
    u32* hbuf   = (u32*)take((size_t)NE * 64 * 4);     // 204.8 MB
    u32* tmp    = (u32*)take((size_t)NN * 64 * 4);     // 12.8 MB
    u32* atomBf = (u32*)take((size_t)NN * ATU * 4);    // 13.6 MB
    int* fidx   = (int*)take((size_t)NE * 4);
    int* sidx   = (int*)take((size_t)NE * 4);
    int* posOf  = (int*)take((size_t)NE * 4);
    int* pidx   = (int*)take((size_t)NE * 4);
    int* cnt    = (int*)take((size_t)NN * 4);
    int* lexc   = (int*)take((size_t)NN * 4);
    int* rowptr = (int*)take((size_t)(NN + 1) * 4);
    int* cursor = (int*)take((size_t)NN * 4);
    int* chunkSum = (int*)take(256 * 4);
    int* chunkOff = (int*)take(256 * 4);
    u32* WiP = (u32*)take(128 * KPU1 * 4);
    u32* WhP = (u32*)take(128 * WHU * 4);
    u32* WoP = (u32*)take(128 * KPU3 * 4);
    // total ~245 MB (round-14 proven footprint)

    cvt_atom<<<2048, 256, 0, stream>>>(atom, atomBf);
    cvt_w<<<48, 256, 0, stream>>>(Wi, WiP, 147, KPU1, 133, 136, 14);
    cvt_w<<<32, 256, 0, stream>>>(Wh, WhP, 128, WHU, 128, 1 << 20, 0);
    cvt_w<<<80, 256, 0, stream>>>(Wo, WoP, 261, KPU3, 133, 136, 128);

    hipMemsetAsync(cnt, 0, (size_t)NN * 4, stream);
    hipMemsetAsync(tmp, 0, (size_t)NN * 64 * 4, stream);   // zero-degree-node safety
    hist<<<1024, 256, 0, stream>>>(dst, cnt);
    scan1<<<NCH, 256, 0, stream>>>(cnt, lexc, chunkSum);
    scan2<<<1, 256, 0, stream>>>(chunkSum, chunkOff);
    scan3<<<NCH, 256, 0, stream>>>(lexc, chunkOff, rowptr, cursor);
    scatter<<<1024, 256, 0, stream>>>(dst, rev, cursor, fidx, sidx, posOf);
    pidx_build<<<1024, 256, 0, stream>>>(fidx, posOf, pidx);

    k_init<<<768, 256, 0, stream>>>(atomBf, bond, fidx, sidx, pidx, WiP, hbuf);   // e-layout
    segsum_s<false><<<3125, 256, 0, stream>>>(sidx, nullptr, hbuf, tmp);          // preload-scan seq
    k_msg_t<false><<<1024, 256, 0, stream>>>(sidx, pidx, WhP, tmp, hbuf);         // all-stream -> f-layout
    segsum_s<true><<<3125, 256, 0, stream>>>(sidx, pidx, hbuf, tmp);              // preload-scan gather
    k_msg_t<true><<<1024, 256, 0, stream>>>(sidx, pidx, WhP, tmp, hbuf);          // random rows -> e-layout
    segsum_s<false><<<3125, 256, 0, stream>>>(sidx, nullptr, hbuf, tmp);          // preload-scan seq
    k_out_p<<<512, 256, 0, stream>>>(atomBf, WoP, tmp, out);
}

// Round 12
// 601.902 us; speedup vs baseline: 1.1452x; 1.0184x over previous
//
#include <hip/hip_runtime.h>

// DMPNN encoder, MI355X bf16-MFMA, round 18: revert to r14 (proven 572.7us)
// + k_init occupancy fix via 32KB LDS + kc4-in-registers.
//
// r17 post-mortem: segsum_s v2 ~90us (serial 64-step shfl scan) still loses
// to segsum_t (~79) -> segsum redesigns permanently abandoned (2 strikes).
// r14 config restored. One change: k_init's Wi tile was 48KB (stride-96 XOR)
// forcing 3 blocks/CU; latency-bound (MfmaUtil 15/VALU 19, occ 28%). Now:
// kc0-3 in 32KB LDS with the k_msg-proven 16-slot XOR (conflict-free), kc4
// tail B held in 32 VGPRs loaded once per wave (zero conflicts, r12 design
// whose crash was workspace-caused, not kernel logic) -> launch_bounds(256,4),
// grid 1024, 16 waves/CU.
//
// Pipeline (pos-space, alternating e-/f-layout; identities:
//   fidx[p]=rev[eidx[p]], sidx[p]=dst[eidx[p]] (sorted),
//   pidx[p]=posOf[fidx[p]] fix-point-free involution):
//   k_init : persistent waves, Wi kc0-3 in LDS / kc4 in regs, e-layout @pidx[p]
//   segsum1: segsum_t<false> sequential
//   k_msg1 : tmp[sidx[p]] - h0@p -> h1 f-layout @p
//   segsum2: segsum_t<true> gather rows pidx[seg]
//   k_msg2 : tmp[sidx[p]] - h1@pidx[p] -> h2 e-layout @pidx[p]
//   segsum3: segsum_t<false> sequential
//   k_out  : persistent 16-node tiles
//
// Weight channel permutation c(p) = (p&64) + 2*(p&15) + ((p>>4)&1) + 32*((p>>5)&1):
// acc pair (2a,2a+1) at lane ln = channels 32a+2ln, 32a+2ln+1; u32 col u holds
// channels 2u,2u+1 (natural order).

typedef unsigned int u32;
typedef unsigned short u16;
using bf16x8 = __attribute__((ext_vector_type(8))) __bf16;
using f32x4  = __attribute__((ext_vector_type(4))) float;

#define NN 50000
#define NP 400000
#define NE 800000
#define AF 133
#define HID 128
#define ATU 68      // atomBf row stride in u32
#define KPU1 80     // Wi packed row stride in u32 (160 cols = 5 kc chunks)
#define WHU 64      // Wh packed row stride (u32) = 256 B rows
#define KPU3 148    // Wo packed row stride; 144 data u32 = 288 cols = 9 chunks
#define KC3 9
#define NCH 196     // scan chunks of 256 covering NN

__device__ __forceinline__ u16 f2bf(float f) {
    union { float f; u32 u; } x; x.f = f;
    u32 r = x.u + 0x7fffu + ((x.u >> 16) & 1u);   // RNE
    return (u16)(r >> 16);
}
__device__ __forceinline__ float bf2f(u16 b) {
    union { u32 u; float f; } x; x.u = ((u32)b) << 16;
    return x.f;
}
__device__ __forceinline__ float lo16(u32 v) { return bf2f((u16)v); }
__device__ __forceinline__ float hi16(u32 v) { return bf2f((u16)(v >> 16)); }
__device__ __forceinline__ u32 pack2(float a, float b) {
    return (u32)f2bf(a) | ((u32)f2bf(b) << 16);
}
__device__ __forceinline__ float relu(float v) { return v > 0.f ? v : 0.f; }

// single-instruction RNE pack of two f32 -> packed bf16x2 (no builtin on gfx950)
__device__ __forceinline__ u32 cvt_pk_bf16(float lo, float hi) {
    u32 r;
    asm("v_cvt_pk_bf16_f32 %0, %1, %2" : "=v"(r) : "v"(lo), "v"(hi));
    return r;
}
__device__ __forceinline__ float bfLO(u32 v) {
    union { u32 u; float f; } x; x.u = v << 16; return x.f;
}
__device__ __forceinline__ float bfHI(u32 v) {
    union { u32 u; float f; } x; x.u = v & 0xffff0000u; return x.f;
}
__device__ __forceinline__ u32 sub2_pk(u32 t, u32 h) {
    return cvt_pk_bf16(bfLO(t) - bfLO(h), bfHI(t) - bfHI(h));
}
__device__ __forceinline__ u32 relu2_pk(float a, float b) {
    return cvt_pk_bf16(a > 0.f ? a : 0.f, b > 0.f ? b : 0.f);
}

union frag_cast { uint4 u; bf16x8 v; };

// ---------------- precompute kernels ----------------

__global__ void cvt_atom(const float* __restrict__ atom, u32* __restrict__ out) {
    int total = NN * ATU;
    for (int i = blockIdx.x * blockDim.x + threadIdx.x; i < total; i += gridDim.x * blockDim.x) {
        int n = i / ATU;
        int cu = i - n * ATU;
        int k = 2 * cu;
        float f0 = (k < AF) ? atom[n * AF + k] : 0.f;
        float f1 = (k + 1 < AF) ? atom[n * AF + k + 1] : 0.f;
        out[i] = pack2(f0, f1);
    }
}

__device__ __forceinline__ float wcol(const float* W, int n, int Kw, int len1, int off2, int len2, int k) {
    if (k < len1) return W[n * Kw + k];
    int j = k - off2;
    if (j >= 0 && j < len2) return W[n * Kw + len1 + j];
    return 0.f;
}
__global__ void cvt_w(const float* __restrict__ W, u32* __restrict__ out,
                      int Kw, int KpU, int len1, int off2, int len2) {
    int total = 128 * KpU;
    for (int i = blockIdx.x * blockDim.x + threadIdx.x; i < total; i += gridDim.x * blockDim.x) {
        int p = i / KpU;
        int cu = i - p * KpU;
        int t = p & 63;
        int c = (p & 64) + 2 * (t & 15) + ((t >> 4) & 1) + 32 * ((t >> 5) & 1);
        int k = 2 * cu;
        out[i] = pack2(wcol(W, c, Kw, len1, off2, len2, k),
                       wcol(W, c, Kw, len1, off2, len2, k + 1));
    }
}

// ---------------- CSR build ----------------

__global__ void hist(const int* __restrict__ dst, int* __restrict__ cnt) {
    for (int e = blockIdx.x * blockDim.x + threadIdx.x; e < NE; e += gridDim.x * blockDim.x)
        atomicAdd(&cnt[dst[e]], 1);
}

__global__ void scan1(const int* __restrict__ cnt, int* __restrict__ lexc, int* __restrict__ chunkSum) {
    __shared__ int s[256];
    int t = threadIdx.x, idx = blockIdx.x * 256 + t;
    int v = (idx < NN) ? cnt[idx] : 0;
    s[t] = v; __syncthreads();
    for (int off = 1; off < 256; off <<= 1) {
        int x = (t >= off) ? s[t - off] : 0;
        __syncthreads();
        s[t] += x;
        __syncthreads();
    }
    if (idx < NN) lexc[idx] = s[t] - v;
    if (t == 255) chunkSum[blockIdx.x] = s[255];
}

__global__ void scan2(const int* __restrict__ chunkSum, int* __restrict__ chunkOff) {
    __shared__ int s[256];
    int t = threadIdx.x;
    int v = (t < NCH) ? chunkSum[t] : 0;
    s[t] = v; __syncthreads();
    for (int off = 1; off < 256; off <<= 1) {
        int x = (t >= off) ? s[t - off] : 0;
        __syncthreads();
        s[t] += x;
        __syncthreads();
    }
    if (t < NCH) chunkOff[t] = s[t] - v;
}

__global__ void scan3(const int* __restrict__ lexc, const int* __restrict__ chunkOff,
                      int* __restrict__ rowptr, int* __restrict__ cursor) {
    int idx = blockIdx.x * 256 + threadIdx.x;
    if (idx < NN) {
        int v = lexc[idx] + chunkOff[blockIdx.x];
        rowptr[idx] = v;
        cursor[idx] = v;
    }
    if (idx == 0) rowptr[NN] = NE;
}

__global__ void scatter(const int* __restrict__ dst, const int* __restrict__ rev,
                        int* __restrict__ cursor, int* __restrict__ fidx,
                        int* __restrict__ sidx, int* __restrict__ posOf) {
    for (int e = blockIdx.x * blockDim.x + threadIdx.x; e < NE; e += gridDim.x * blockDim.x) {
        int d = dst[e];
        int pos = atomicAdd(&cursor[d], 1);
        fidx[pos] = rev[e];
        sidx[pos] = d;        // = src[fidx[pos]], nondecreasing over pos
        posOf[e] = pos;
    }
}

__global__ void pidx_build(const int* __restrict__ fidx, const int* __restrict__ posOf,
                           int* __restrict__ pidx) {
    for (int p = blockIdx.x * blockDim.x + threadIdx.x; p < NE; p += gridDim.x * blockDim.x)
        pidx[p] = posOf[fidx[p]];
}

// ---------------- segment sum ----------------
template<bool G>
__global__ __launch_bounds__(256)
void segsum_t(const int* __restrict__ rowptr, const int* __restrict__ gat,
              const u32* __restrict__ h, u32* __restrict__ tmp) {
    const int lane = threadIdx.x & 63;
    const int wv = threadIdx.x >> 6;
    const int rsel = lane >> 4;
    const int cg = lane & 15;
    const int nwaves = gridDim.x * 4;
    for (int n = blockIdx.x * 4 + wv; n < NN; n += nwaves) {
        int beg = rowptr[n], end = rowptr[n + 1];
        float a0 = 0, a1 = 0, a2 = 0, a3 = 0, a4 = 0, a5 = 0, a6 = 0, a7 = 0;
        int i = beg;
        for (; i + 8 <= end; i += 8) {
            int rA = G ? gat[i + rsel] : (i + rsel);
            int rB = G ? gat[i + 4 + rsel] : (i + 4 + rsel);
            uint4 hA = *(const uint4*)(h + (size_t)rA * 64 + 4 * cg);
            uint4 hB = *(const uint4*)(h + (size_t)rB * 64 + 4 * cg);
            a0 += lo16(hA.x) + lo16(hB.x); a1 += hi16(hA.x) + hi16(hB.x);
            a2 += lo16(hA.y) + lo16(hB.y); a3 += hi16(hA.y) + hi16(hB.y);
            a4 += lo16(hA.z) + lo16(hB.z); a5 += hi16(hA.z) + hi16(hB.z);
            a6 += lo16(hA.w) + lo16(hB.w); a7 += hi16(hA.w) + hi16(hB.w);
        }
        for (; i < end; i += 4) {
            if (i + rsel < end) {
                int rA = G ? gat[i + rsel] : (i + rsel);
                uint4 hA = *(const uint4*)(h + (size_t)rA * 64 + 4 * cg);
                a0 += lo16(hA.x); a1 += hi16(hA.x);
                a2 += lo16(hA.y); a3 += hi16(hA.y);
                a4 += lo16(hA.z); a5 += hi16(hA.z);
                a6 += lo16(hA.w); a7 += hi16(hA.w);
            }
        }
        a0 += __shfl_xor(a0, 16); a0 += __shfl_xor(a0, 32);
        a1 += __shfl_xor(a1, 16); a1 += __shfl_xor(a1, 32);
        a2 += __shfl_xor(a2, 16); a2 += __shfl_xor(a2, 32);
        a3 += __shfl_xor(a3, 16); a3 += __shfl_xor(a3, 32);
        a4 += __shfl_xor(a4, 16); a4 += __shfl_xor(a4, 32);
        a5 += __shfl_xor(a5, 16); a5 += __shfl_xor(a5, 32);
        a6 += __shfl_xor(a6, 16); a6 += __shfl_xor(a6, 32);
        a7 += __shfl_xor(a7, 16); a7 += __shfl_xor(a7, 32);
        if (rsel == 0) {
            uint4 o;
            o.x = pack2(a0, a1); o.y = pack2(a2, a3);
            o.z = pack2(a4, a5); o.w = pack2(a6, a7);
            *(uint4*)(tmp + (size_t)n * 64 + 4 * cg) = o;
        }
    }
}

// ---------------- k_init: persistent waves, VMEM-free MFMA loop ----------------
// Wi kc0-3 (slots 0..15) in 32KB LDS with the k_msg-proven XOR swizzle
// (phys slot = slot ^ (row&15), conflict-free); kc4 tail B fragments held in
// 32 VGPRs per wave (loaded once). 4 blocks/CU, 16 waves/CU.
__global__ __launch_bounds__(256, 4)
void k_init(const u32* __restrict__ atomBf, const float* __restrict__ bond,
            const int* __restrict__ fidx, const int* __restrict__ sidx,
            const int* __restrict__ pidx, const u32* __restrict__ Wp,
            u32* __restrict__ hout)
{
    __shared__ u32 Wlds[128 * 64];   // 32768 B -> 4 blocks/CU
    const int tid  = threadIdx.x;
    const int lane = tid & 63;
    const int wv   = tid >> 6;
    const int ln   = lane & 15;
    const int q    = lane >> 4;

    // stage kc0-3 (slots 0..15) with XOR swizzle; kc4 tail -> registers
    {
        const int row = tid >> 1;        // 128 rows, 2 threads/row
        const int half = tid & 1;        // 8 slots of 16 B each
        const int rx = row & 15;
        #pragma unroll
        for (int sl = 0; sl < 8; ++sl) {
            int L = half * 8 + sl;       // 0..15
            int P = L ^ rx;
            *(uint4*)(Wlds + row * 64 + P * 4) = *(const uint4*)(Wp + row * KPU1 + L * 4);
        }
    }
    bf16x8 bk4[8];
    #pragma unroll
    for (int j = 0; j < 8; ++j)
        bk4[j] = *(const bf16x8*)(Wp + (size_t)(16 * j + ln) * KPU1 + (16 + q) * 4);
    __syncthreads();

    const int NT = NE / 16;              // 50000 tiles of 16 rows
    const int stride = gridDim.x * 4;
    int s = blockIdx.x * 4 + wv;
    if (s >= NT) return;

    uint4  rA[4];
    uint4  rA4;
    float2 b01, b23, b45, b67;
    int4   stA;

    {
        int p = s * 16 + ln;
        int sr = sidx[p];
        int fr = fidx[p];
        stA = *(const int4*)(pidx + s * 16 + 4 * q);
        const u32* ab = atomBf + (size_t)sr * ATU;
        #pragma unroll
        for (int kc = 0; kc < 4; ++kc)
            rA[kc] = *(const uint4*)(ab + kc * 16 + q * 4);
        if (q == 0) rA4 = *(const uint4*)(ab + 64);
        const float* bp = bond + (size_t)fr * 14;
        if (q == 1) {
            b01 = *(const float2*)(bp + 0); b23 = *(const float2*)(bp + 2);
            b45 = *(const float2*)(bp + 4); b67 = *(const float2*)(bp + 6);
        } else if (q == 2) {
            b01 = *(const float2*)(bp + 8); b23 = *(const float2*)(bp + 10);
            b45 = *(const float2*)(bp + 12);
        }
    }

    while (true) {
        const int sn = s + stride;
        const bool more = sn < NT;       // wave-uniform

        int srB = 0, frB = 0;
        int4 stB;
        if (more) {
            int p = sn * 16 + ln;
            srB = sidx[p];
            frB = fidx[p];
            stB = *(const int4*)(pidx + sn * 16 + 4 * q);
        }

        bf16x8 aF[5];
        #pragma unroll
        for (int kc = 0; kc < 4; ++kc) { frag_cast fc; fc.u = rA[kc]; aF[kc] = fc.v; }
        {
            frag_cast f4;
            if (q == 0)      f4.u = rA4;
            else if (q == 1) f4.u = make_uint4(cvt_pk_bf16(b01.x, b01.y), cvt_pk_bf16(b23.x, b23.y),
                                               cvt_pk_bf16(b45.x, b45.y), cvt_pk_bf16(b67.x, b67.y));
            else if (q == 2) f4.u = make_uint4(cvt_pk_bf16(b01.x, b01.y), cvt_pk_bf16(b23.x, b23.y),
                                               cvt_pk_bf16(b45.x, b45.y), 0u);
            else             f4.u = make_uint4(0u, 0u, 0u, 0u);
            aF[4] = f4.v;
        }

        if (more) {
            const u32* ab = atomBf + (size_t)srB * ATU;
            #pragma unroll
            for (int kc = 0; kc < 4; ++kc)
                rA[kc] = *(const uint4*)(ab + kc * 16 + q * 4);
            if (q == 0) rA4 = *(const uint4*)(ab + 64);
            const float* bp = bond + (size_t)frB * 14;
            if (q == 1) {
                b01 = *(const float2*)(bp + 0); b23 = *(const float2*)(bp + 2);
                b45 = *(const float2*)(bp + 4); b67 = *(const float2*)(bp + 6);
            } else if (q == 2) {
                b01 = *(const float2*)(bp + 8); b23 = *(const float2*)(bp + 10);
                b45 = *(const float2*)(bp + 12);
            }
        }

        // MFMA 16x128, K=160; kc0-3 B from LDS (XOR), kc4 B from registers.
        u32 zoff = 0;
        asm volatile("" : "+v"(zoff));   // defeat LICM: keep B ds_reads in-loop
        f32x4 acc[8] = {};
        #pragma unroll
        for (int kc = 0; kc < 4; ++kc) {
            const u32* wrow = Wlds + zoff + ln * 64 + (((kc * 4 + q) ^ ln) << 2);
            #pragma unroll
            for (int j = 0; j < 8; ++j) {
                bf16x8 b = *(const bf16x8*)(wrow + j * 1024);
                acc[j] = __builtin_amdgcn_mfma_f32_16x16x32_bf16(aF[kc], b, acc[j], 0, 0, 0);
            }
        }
        #pragma unroll
        for (int j = 0; j < 8; ++j)
            acc[j] = __builtin_amdgcn_mfma_f32_16x16x32_bf16(aF[4], bk4[j], acc[j], 0, 0, 0);

        #pragma unroll
        for (int r = 0; r < 4; ++r) {
            int wrow = (r == 0) ? stA.x : (r == 1) ? stA.y : (r == 2) ? stA.z : stA.w;
            u32* orow = hout + (size_t)wrow * 64;
            #pragma unroll
            for (int a = 0; a < 4; ++a)
                orow[16 * a + ln] = relu2_pk(acc[2 * a][r], acc[2 * a + 1][r]);
        }

        if (!more) break;
        s = sn;
        stA = stB;
    }
}

// ---------------- k_msg: persistent waves, VMEM-free MFMA loop ----------------
template<bool USEIDX>
__global__ __launch_bounds__(256, 4)
void k_msg_t(const int* __restrict__ sidx, const int* __restrict__ pidx,
             const u32* __restrict__ Wp, const u32* __restrict__ tmp,
             u32* __restrict__ h)
{
    __shared__ u32 Wlds[128 * 64];   // 32 KB; slot phys = slot ^ (row&15)
    const int tid  = threadIdx.x;
    const int lane = tid & 63;
    const int wv   = tid >> 6;
    const int ln   = lane & 15;
    const int q    = lane >> 4;

    {
        const int row = tid >> 1;        // 128 rows, 2 threads/row
        const int half = tid & 1;        // 8 slots of 16 B each
        const int rx = row & 15;
        #pragma unroll
        for (int sl = 0; sl < 8; ++sl) {
            int L = half * 8 + sl;
            int P = L ^ rx;
            *(uint4*)(Wlds + row * 64 + P * 4) = *(const uint4*)(Wp + row * 64 + L * 4);
        }
    }
    __syncthreads();

    const int NT = NE / 16;              // 50000 tiles of 16 rows
    const int stride = gridDim.x * 4;
    int s = blockIdx.x * 4 + wv;
    if (s >= NT) return;

    int4  stA;
    uint4 tv[4], hv[4];

    {
        int p = s * 16 + ln;
        int sr = sidx[p];
        int hr = USEIDX ? pidx[p] : p;
        if (USEIDX) stA = *(const int4*)(pidx + s * 16 + 4 * q);
        const u32* tb = tmp + (size_t)sr * 64 + q * 4;
        const u32* hb = h   + (size_t)hr * 64 + q * 4;
        #pragma unroll
        for (int kc = 0; kc < 4; ++kc) {
            tv[kc] = *(const uint4*)(tb + kc * 16);
            hv[kc] = *(const uint4*)(hb + kc * 16);
        }
    }

    while (true) {
        const int sn = s + stride;
        const bool more = sn < NT;       // wave-uniform

        int srB = 0, hrB = 0;
        int4 stB;
        if (more) {
            int p = sn * 16 + ln;
            srB = sidx[p];
            hrB = USEIDX ? pidx[p] : p;
            if (USEIDX) stB = *(const int4*)(pidx + sn * 16 + 4 * q);
        }

        bf16x8 aF[4];
        #pragma unroll
        for (int kc = 0; kc < 4; ++kc) {
            frag_cast fc;
            fc.u.x = sub2_pk(tv[kc].x, hv[kc].x);
            fc.u.y = sub2_pk(tv[kc].y, hv[kc].y);
            fc.u.z = sub2_pk(tv[kc].z, hv[kc].z);
            fc.u.w = sub2_pk(tv[kc].w, hv[kc].w);
            aF[kc] = fc.v;
        }

        if (more) {
            const u32* tb = tmp + (size_t)srB * 64 + q * 4;
            const u32* hb = h   + (size_t)hrB * 64 + q * 4;
            #pragma unroll
            for (int kc = 0; kc < 4; ++kc) {
                tv[kc] = *(const uint4*)(tb + kc * 16);
                hv[kc] = *(const uint4*)(hb + kc * 16);
            }
        }

        u32 zoff = 0;
        asm volatile("" : "+v"(zoff));   // defeat LICM: keep B ds_reads in-loop
        f32x4 acc[8] = {};
        #pragma unroll
        for (int kc = 0; kc < 4; ++kc) {
            const u32* wrow = Wlds + zoff + ln * 64 + (((kc * 4 + q) ^ ln) << 2);
            #pragma unroll
            for (int j = 0; j < 8; ++j) {
                bf16x8 b = *(const bf16x8*)(wrow + j * 1024);
                acc[j] = __builtin_amdgcn_mfma_f32_16x16x32_bf16(aF[kc], b, acc[j], 0, 0, 0);
            }
        }

        #pragma unroll
        for (int r = 0; r < 4; ++r) {
            int wrow = USEIDX
                ? ((r == 0) ? stA.x : (r == 1) ? stA.y : (r == 2) ? stA.z : stA.w)
                : (s * 16 + 4 * q + r);
            u32* orow = h + (size_t)wrow * 64;
            #pragma unroll
            for (int a = 0; a < 4; ++a)
                orow[16 * a + ln] = relu2_pk(acc[2 * a][r], acc[2 * a + 1][r]);
        }

        if (!more) break;
        s = sn;
        if (USEIDX) stA = stB;
    }
}

// ---------------- k_out: persistent 16-node tiles, VMEM-free MFMA loop ----------------
__global__ __launch_bounds__(256, 2)
void k_out_p(const u32* __restrict__ atomBf, const u32* __restrict__ Wp,
             const u32* __restrict__ tmp, float* __restrict__ out)
{
    __shared__ u32 Wlds[128 * KPU3];   // 75776 B -> 2 blocks/CU
    const int tid  = threadIdx.x;
    const int lane = tid & 63;
    const int wv   = tid >> 6;
    const int ln   = lane & 15;
    const int q    = lane >> 4;

    {
        const int row = tid >> 1;        // 128 rows, 2 threads/row
        const int half = tid & 1;        // 18 slots of 16 B each
        #pragma unroll
        for (int sl = 0; sl < 18; ++sl) {
            int L = half * 18 + sl;      // 0..35
            *(uint4*)(Wlds + row * KPU3 + L * 4) = *(const uint4*)(Wp + row * KPU3 + L * 4);
        }
    }
    __syncthreads();

    const int NT = NN / 16;              // 3125 tiles of 16 nodes
    const int stride = gridDim.x * 4;
    int s = blockIdx.x * 4 + wv;
    if (s >= NT) return;

    uint4 rA[9];
    auto gather = [&](int ss, uint4* r) {
        int n = ss * 16 + ln;
        const u32* ab = atomBf + (size_t)n * ATU;
        const u32* tp = tmp + (size_t)n * 64;
        #pragma unroll
        for (int kc = 0; kc < 4; ++kc)
            r[kc] = *(const uint4*)(ab + kc * 16 + q * 4);
        if (q == 0) {
            r[4] = *(const uint4*)(ab + 64);
            r[5] = *(const uint4*)(tp + 12);
            r[6] = *(const uint4*)(tp + 28);
            r[7] = *(const uint4*)(tp + 44);
            r[8] = *(const uint4*)(tp + 60);
        } else {
            r[4] = *(const uint4*)(tp + (q - 1) * 4);
            r[5] = *(const uint4*)(tp + 12 + q * 4);
            r[6] = *(const uint4*)(tp + 28 + q * 4);
            r[7] = *(const uint4*)(tp + 44 + q * 4);
            r[8] = make_uint4(0u, 0u, 0u, 0u);
        }
    };

    gather(s, rA);

    while (true) {
        const int sn = s + stride;
        const bool more = sn < NT;       // wave-uniform

        bf16x8 aF[9];
        #pragma unroll
        for (int kc = 0; kc < 9; ++kc) { frag_cast fc; fc.u = rA[kc]; aF[kc] = fc.v; }

        if (more) gather(sn, rA);        // prefetch rides through MFMA (LDS B)

        u32 zoff = 0;
        asm volatile("" : "+v"(zoff));   // defeat LICM: keep B ds_reads in-loop
        f32x4 acc[8] = {};
        #pragma unroll
        for (int kc = 0; kc < KC3; ++kc) {
            const u32* wrow = Wlds + zoff + ln * KPU3 + (kc * 4 + q) * 4;
            #pragma unroll
            for (int j = 0; j < 8; ++j) {
                bf16x8 b = *(const bf16x8*)(wrow + j * (16 * KPU3));
                acc[j] = __builtin_amdgcn_mfma_f32_16x16x32_bf16(aF[kc], b, acc[j], 0, 0, 0);
            }
        }

        // store: 16 nodes x 128 f32; channel(a, ln) = 32a + 2ln (+1)
        #pragma unroll
        for (int r = 0; r < 4; ++r) {
            int n = s * 16 + 4 * q + r;
            float2* orow = (float2*)(out + (size_t)n * HID);
            #pragma unroll
            for (int a = 0; a < 4; ++a) {
                float2 v;
                v.x = relu(acc[2 * a][r]);
                v.y = relu(acc[2 * a + 1][r]);
                orow[16 * a + ln] = v;
            }
        }

        if (!more) break;
        s = sn;
    }
}

// ---------------- launch ----------------

extern "C" void kernel_launch(void* const* d_in, const int* in_sizes, int n_in,
                              void* d_out, int out_size, void* d_ws, size_t ws_size,
                              hipStream_t stream) {
    const float* atom = (const float*)d_in[0];   // [50000][133]
    const float* bond = (const float*)d_in[1];   // [800000][14]
    const float* Wi   = (const float*)d_in[2];   // [128][147]
    const float* Wh   = (const float*)d_in[3];   // [128][128]
    const float* Wo   = (const float*)d_in[4];   // [128][261]
    const int*   src  = (const int*)d_in[5]; (void)src;
    const int*   dst  = (const int*)d_in[6];
    const int*   rev  = (const int*)d_in[7];
    float* out = (float*)d_out;

    char* ws = (char*)d_ws;
    size_t off = 0;
    auto take = [&](size_t bytes) { char* p = ws + off; off = (off + bytes + 255) & ~(size_t)255; return p; };
    u32* hbuf   = (u32*)take((size_t)NE * 64 * 4);     // 204.8 MB
    u32* tmp    = (u32*)take((size_t)NN * 64 * 4);     // 12.8 MB
    u32* atomBf = (u32*)take((size_t)NN * ATU * 4);    // 13.6 MB
    int* fidx   = (int*)take((size_t)NE * 4);
    int* sidx   = (int*)take((size_t)NE * 4);
    int* posOf  = (int*)take((size_t)NE * 4);
    int* pidx   = (int*)take((size_t)NE * 4);
    int* cnt    = (int*)take((size_t)NN * 4);
    int* lexc   = (int*)take((size_t)NN * 4);
    int* rowptr = (int*)take((size_t)(NN + 1) * 4);
    int* cursor = (int*)take((size_t)NN * 4);
    int* chunkSum = (int*)take(256 * 4);
    int* chunkOff = (int*)take(256 * 4);
    u32* WiP = (u32*)take(128 * KPU1 * 4);
    u32* WhP = (u32*)take(128 * WHU * 4);
    u32* WoP = (u32*)take(128 * KPU3 * 4);
    // total ~245 MB (round-14 proven footprint)

    cvt_atom<<<2048, 256, 0, stream>>>(atom, atomBf);
    cvt_w<<<48, 256, 0, stream>>>(Wi, WiP, 147, KPU1, 133, 136, 14);
    cvt_w<<<32, 256, 0, stream>>>(Wh, WhP, 128, WHU, 128, 1 << 20, 0);
    cvt_w<<<80, 256, 0, stream>>>(Wo, WoP, 261, KPU3, 133, 136, 128);

    hipMemsetAsync(cnt, 0, (size_t)NN * 4, stream);
    hist<<<1024, 256, 0, stream>>>(dst, cnt);
    scan1<<<NCH, 256, 0, stream>>>(cnt, lexc, chunkSum);
    scan2<<<1, 256, 0, stream>>>(chunkSum, chunkOff);
    scan3<<<NCH, 256, 0, stream>>>(lexc, chunkOff, rowptr, cursor);
    scatter<<<1024, 256, 0, stream>>>(dst, rev, cursor, fidx, sidx, posOf);
    pidx_build<<<1024, 256, 0, stream>>>(fidx, posOf, pidx);

    k_init<<<1024, 256, 0, stream>>>(atomBf, bond, fidx, sidx, pidx, WiP, hbuf);  // e-layout
    segsum_t<false><<<2048, 256, 0, stream>>>(rowptr, nullptr, hbuf, tmp);        // sequential
    k_msg_t<false><<<1024, 256, 0, stream>>>(sidx, pidx, WhP, tmp, hbuf);         // all-stream -> f-layout
    segsum_t<true><<<2048, 256, 0, stream>>>(rowptr, pidx, hbuf, tmp);            // gather
    k_msg_t<true><<<1024, 256, 0, stream>>>(sidx, pidx, WhP, tmp, hbuf);          // random rows -> e-layout
    segsum_t<false><<<2048, 256, 0, stream>>>(rowptr, nullptr, hbuf, tmp);        // sequential
    k_out_p<<<512, 256, 0, stream>>>(atomBf, WoP, tmp, out);
}

// Round 13
// 580.884 us; speedup vs baseline: 1.1866x; 1.0362x over previous
//
#include <hip/hip_runtime.h>

// DMPNN encoder, MI355X bf16-MFMA, round 19: exact r14 revert (proven 572.7us)
// + XCD-aware block swizzle (T1) on all persistent/strided kernels.
//
// r18 post-mortem: k_init 4-blocks/CU regressed 84->106us, FETCH 81->138MB --
// more concurrent tiles thrashed the sorted-sidx L2 locality. Occupancy
// levers are exhausted on all three MFMA kernels (r11 neutral, r18 negative);
// the binding constraint is traffic/locality. T1: default dispatch round-
// robins consecutive blocks across the 8 XCD L2s, so each 4MB L2 sees the
// whole tmp (12.8MB) / atomBf (13.6MB) / hbuf stream. swz = (bid&7)*(g/8) +
// (bid>>3) (bijective, all grids %8==0) gives each XCD a contiguous block
// chunk -> contiguous pos/node ranges (sidx sorted) -> per-XCD slices
// ~1.7MB, L2-resident. Applied to k_init, k_msg x2, segsum_t x3, k_out_p.
//
// Pipeline (pos-space, alternating e-/f-layout; identities:
//   fidx[p]=rev[eidx[p]], sidx[p]=dst[eidx[p]] (sorted),
//   pidx[p]=posOf[fidx[p]] fix-point-free involution):
//   k_init : persistent waves, Wi in LDS (96-stride 24-slot XOR), e-layout @pidx[p]
//   segsum1: sequential | k_msg1 -> f-layout | segsum2: gather | k_msg2 ->
//   e-layout | segsum3: sequential | k_out: persistent 16-node tiles
//
// Weight channel permutation c(p) = (p&64) + 2*(p&15) + ((p>>4)&1) + 32*((p>>5)&1):
// acc pair (2a,2a+1) at lane ln = channels 32a+2ln, 32a+2ln+1; u32 col u holds
// channels 2u,2u+1 (natural order).

typedef unsigned int u32;
typedef unsigned short u16;
using bf16x8 = __attribute__((ext_vector_type(8))) __bf16;
using f32x4  = __attribute__((ext_vector_type(4))) float;

#define NN 50000
#define NP 400000
#define NE 800000
#define AF 133
#define HID 128
#define ATU 68      // atomBf row stride in u32
#define KPU1 80     // Wi packed row stride in u32 (160 cols = 5 kc chunks)
#define WHU 64      // Wh packed row stride (u32) = 256 B rows
#define KPU3 148    // Wo packed row stride; 144 data u32 = 288 cols = 9 chunks
#define KC3 9
#define NCH 196     // scan chunks of 256 covering NN

__device__ __forceinline__ u16 f2bf(float f) {
    union { float f; u32 u; } x; x.f = f;
    u32 r = x.u + 0x7fffu + ((x.u >> 16) & 1u);   // RNE
    return (u16)(r >> 16);
}
__device__ __forceinline__ float bf2f(u16 b) {
    union { u32 u; float f; } x; x.u = ((u32)b) << 16;
    return x.f;
}
__device__ __forceinline__ float lo16(u32 v) { return bf2f((u16)v); }
__device__ __forceinline__ float hi16(u32 v) { return bf2f((u16)(v >> 16)); }
__device__ __forceinline__ u32 pack2(float a, float b) {
    return (u32)f2bf(a) | ((u32)f2bf(b) << 16);
}
__device__ __forceinline__ float relu(float v) { return v > 0.f ? v : 0.f; }

// single-instruction RNE pack of two f32 -> packed bf16x2 (no builtin on gfx950)
__device__ __forceinline__ u32 cvt_pk_bf16(float lo, float hi) {
    u32 r;
    asm("v_cvt_pk_bf16_f32 %0, %1, %2" : "=v"(r) : "v"(lo), "v"(hi));
    return r;
}
__device__ __forceinline__ float bfLO(u32 v) {
    union { u32 u; float f; } x; x.u = v << 16; return x.f;
}
__device__ __forceinline__ float bfHI(u32 v) {
    union { u32 u; float f; } x; x.u = v & 0xffff0000u; return x.f;
}
__device__ __forceinline__ u32 sub2_pk(u32 t, u32 h) {
    return cvt_pk_bf16(bfLO(t) - bfLO(h), bfHI(t) - bfHI(h));
}
__device__ __forceinline__ u32 relu2_pk(float a, float b) {
    return cvt_pk_bf16(a > 0.f ? a : 0.f, b > 0.f ? b : 0.f);
}

// XCD-aware block swizzle: contiguous block chunk per XCD (grid % 8 == 0)
__device__ __forceinline__ int xcd_swz(int bid, int grid) {
    return (bid & 7) * (grid >> 3) + (bid >> 3);
}

union frag_cast { uint4 u; bf16x8 v; };

// ---------------- precompute kernels ----------------

__global__ void cvt_atom(const float* __restrict__ atom, u32* __restrict__ out) {
    int total = NN * ATU;
    for (int i = blockIdx.x * blockDim.x + threadIdx.x; i < total; i += gridDim.x * blockDim.x) {
        int n = i / ATU;
        int cu = i - n * ATU;
        int k = 2 * cu;
        float f0 = (k < AF) ? atom[n * AF + k] : 0.f;
        float f1 = (k + 1 < AF) ? atom[n * AF + k + 1] : 0.f;
        out[i] = pack2(f0, f1);
    }
}

__device__ __forceinline__ float wcol(const float* W, int n, int Kw, int len1, int off2, int len2, int k) {
    if (k < len1) return W[n * Kw + k];
    int j = k - off2;
    if (j >= 0 && j < len2) return W[n * Kw + len1 + j];
    return 0.f;
}
__global__ void cvt_w(const float* __restrict__ W, u32* __restrict__ out,
                      int Kw, int KpU, int len1, int off2, int len2) {
    int total = 128 * KpU;
    for (int i = blockIdx.x * blockDim.x + threadIdx.x; i < total; i += gridDim.x * blockDim.x) {
        int p = i / KpU;
        int cu = i - p * KpU;
        int t = p & 63;
        int c = (p & 64) + 2 * (t & 15) + ((t >> 4) & 1) + 32 * ((t >> 5) & 1);
        int k = 2 * cu;
        out[i] = pack2(wcol(W, c, Kw, len1, off2, len2, k),
                       wcol(W, c, Kw, len1, off2, len2, k + 1));
    }
}

// ---------------- CSR build ----------------

__global__ void hist(const int* __restrict__ dst, int* __restrict__ cnt) {
    for (int e = blockIdx.x * blockDim.x + threadIdx.x; e < NE; e += gridDim.x * blockDim.x)
        atomicAdd(&cnt[dst[e]], 1);
}

__global__ void scan1(const int* __restrict__ cnt, int* __restrict__ lexc, int* __restrict__ chunkSum) {
    __shared__ int s[256];
    int t = threadIdx.x, idx = blockIdx.x * 256 + t;
    int v = (idx < NN) ? cnt[idx] : 0;
    s[t] = v; __syncthreads();
    for (int off = 1; off < 256; off <<= 1) {
        int x = (t >= off) ? s[t - off] : 0;
        __syncthreads();
        s[t] += x;
        __syncthreads();
    }
    if (idx < NN) lexc[idx] = s[t] - v;
    if (t == 255) chunkSum[blockIdx.x] = s[255];
}

__global__ void scan2(const int* __restrict__ chunkSum, int* __restrict__ chunkOff) {
    __shared__ int s[256];
    int t = threadIdx.x;
    int v = (t < NCH) ? chunkSum[t] : 0;
    s[t] = v; __syncthreads();
    for (int off = 1; off < 256; off <<= 1) {
        int x = (t >= off) ? s[t - off] : 0;
        __syncthreads();
        s[t] += x;
        __syncthreads();
    }
    if (t < NCH) chunkOff[t] = s[t] - v;
}

__global__ void scan3(const int* __restrict__ lexc, const int* __restrict__ chunkOff,
                      int* __restrict__ rowptr, int* __restrict__ cursor) {
    int idx = blockIdx.x * 256 + threadIdx.x;
    if (idx < NN) {
        int v = lexc[idx] + chunkOff[blockIdx.x];
        rowptr[idx] = v;
        cursor[idx] = v;
    }
    if (idx == 0) rowptr[NN] = NE;
}

__global__ void scatter(const int* __restrict__ dst, const int* __restrict__ rev,
                        int* __restrict__ cursor, int* __restrict__ fidx,
                        int* __restrict__ sidx, int* __restrict__ posOf) {
    for (int e = blockIdx.x * blockDim.x + threadIdx.x; e < NE; e += gridDim.x * blockDim.x) {
        int d = dst[e];
        int pos = atomicAdd(&cursor[d], 1);
        fidx[pos] = rev[e];
        sidx[pos] = d;        // = src[fidx[pos]], nondecreasing over pos
        posOf[e] = pos;
    }
}

__global__ void pidx_build(const int* __restrict__ fidx, const int* __restrict__ posOf,
                           int* __restrict__ pidx) {
    for (int p = blockIdx.x * blockDim.x + threadIdx.x; p < NE; p += gridDim.x * blockDim.x)
        pidx[p] = posOf[fidx[p]];
}

// ---------------- segment sum ----------------
template<bool G>
__global__ __launch_bounds__(256)
void segsum_t(const int* __restrict__ rowptr, const int* __restrict__ gat,
              const u32* __restrict__ h, u32* __restrict__ tmp) {
    const int lane = threadIdx.x & 63;
    const int wv = threadIdx.x >> 6;
    const int rsel = lane >> 4;
    const int cg = lane & 15;
    const int nwaves = gridDim.x * 4;
    const int sb = xcd_swz(blockIdx.x, gridDim.x);
    for (int n = sb * 4 + wv; n < NN; n += nwaves) {
        int beg = rowptr[n], end = rowptr[n + 1];
        float a0 = 0, a1 = 0, a2 = 0, a3 = 0, a4 = 0, a5 = 0, a6 = 0, a7 = 0;
        int i = beg;
        for (; i + 8 <= end; i += 8) {
            int rA = G ? gat[i + rsel] : (i + rsel);
            int rB = G ? gat[i + 4 + rsel] : (i + 4 + rsel);
            uint4 hA = *(const uint4*)(h + (size_t)rA * 64 + 4 * cg);
            uint4 hB = *(const uint4*)(h + (size_t)rB * 64 + 4 * cg);
            a0 += lo16(hA.x) + lo16(hB.x); a1 += hi16(hA.x) + hi16(hB.x);
            a2 += lo16(hA.y) + lo16(hB.y); a3 += hi16(hA.y) + hi16(hB.y);
            a4 += lo16(hA.z) + lo16(hB.z); a5 += hi16(hA.z) + hi16(hB.z);
            a6 += lo16(hA.w) + lo16(hB.w); a7 += hi16(hA.w) + hi16(hB.w);
        }
        for (; i < end; i += 4) {
            if (i + rsel < end) {
                int rA = G ? gat[i + rsel] : (i + rsel);
                uint4 hA = *(const uint4*)(h + (size_t)rA * 64 + 4 * cg);
                a0 += lo16(hA.x); a1 += hi16(hA.x);
                a2 += lo16(hA.y); a3 += hi16(hA.y);
                a4 += lo16(hA.z); a5 += hi16(hA.z);
                a6 += lo16(hA.w); a7 += hi16(hA.w);
            }
        }
        a0 += __shfl_xor(a0, 16); a0 += __shfl_xor(a0, 32);
        a1 += __shfl_xor(a1, 16); a1 += __shfl_xor(a1, 32);
        a2 += __shfl_xor(a2, 16); a2 += __shfl_xor(a2, 32);
        a3 += __shfl_xor(a3, 16); a3 += __shfl_xor(a3, 32);
        a4 += __shfl_xor(a4, 16); a4 += __shfl_xor(a4, 32);
        a5 += __shfl_xor(a5, 16); a5 += __shfl_xor(a5, 32);
        a6 += __shfl_xor(a6, 16); a6 += __shfl_xor(a6, 32);
        a7 += __shfl_xor(a7, 16); a7 += __shfl_xor(a7, 32);
        if (rsel == 0) {
            uint4 o;
            o.x = pack2(a0, a1); o.y = pack2(a2, a3);
            o.z = pack2(a4, a5); o.w = pack2(a6, a7);
            *(uint4*)(tmp + (size_t)n * 64 + 4 * cg) = o;
        }
    }
}

// ---------------- k_init: persistent waves, VMEM-free MFMA loop ----------------
// (r14 proven form: stride-96 LDS, 24-slot XOR with rx=row&7, 3 blocks/CU)
__global__ __launch_bounds__(256, 3)
void k_init(const u32* __restrict__ atomBf, const float* __restrict__ bond,
            const int* __restrict__ fidx, const int* __restrict__ sidx,
            const int* __restrict__ pidx, const u32* __restrict__ Wp,
            u32* __restrict__ hout)
{
    __shared__ u32 Wlds[128 * 96];   // 49152 B; phys slot = slot ^ (row&7)
    const int tid  = threadIdx.x;
    const int lane = tid & 63;
    const int wv   = tid >> 6;
    const int ln   = lane & 15;
    const int q    = lane >> 4;

    {
        const int row = tid >> 1;        // 128 rows, 2 threads/row
        const int half = tid & 1;        // 10 slots of 16 B each
        const int rx = row & 7;
        #pragma unroll
        for (int sl = 0; sl < 10; ++sl) {
            int L = half * 10 + sl;      // 0..19
            int P = L ^ rx;              // <= 23, fits 24-slot stride
            *(uint4*)(Wlds + row * 96 + P * 4) = *(const uint4*)(Wp + row * KPU1 + L * 4);
        }
    }
    __syncthreads();

    const int NT = NE / 16;              // 50000 tiles of 16 rows
    const int stride = gridDim.x * 4;
    const int sb = xcd_swz(blockIdx.x, gridDim.x);
    int s = sb * 4 + wv;
    if (s >= NT) return;

    uint4  rA[4];
    uint4  rA4;
    float2 b01, b23, b45, b67;
    int4   stA;

    {
        int p = s * 16 + ln;
        int sr = sidx[p];
        int fr = fidx[p];
        stA = *(const int4*)(pidx + s * 16 + 4 * q);
        const u32* ab = atomBf + (size_t)sr * ATU;
        #pragma unroll
        for (int kc = 0; kc < 4; ++kc)
            rA[kc] = *(const uint4*)(ab + kc * 16 + q * 4);
        if (q == 0) rA4 = *(const uint4*)(ab + 64);
        const float* bp = bond + (size_t)fr * 14;
        if (q == 1) {
            b01 = *(const float2*)(bp + 0); b23 = *(const float2*)(bp + 2);
            b45 = *(const float2*)(bp + 4); b67 = *(const float2*)(bp + 6);
        } else if (q == 2) {
            b01 = *(const float2*)(bp + 8); b23 = *(const float2*)(bp + 10);
            b45 = *(const float2*)(bp + 12);
        }
    }

    while (true) {
        const int sn = s + stride;
        const bool more = sn < NT;       // wave-uniform

        int srB = 0, frB = 0;
        int4 stB;
        if (more) {
            int p = sn * 16 + ln;
            srB = sidx[p];
            frB = fidx[p];
            stB = *(const int4*)(pidx + sn * 16 + 4 * q);
        }

        bf16x8 aF[5];
        #pragma unroll
        for (int kc = 0; kc < 4; ++kc) { frag_cast fc; fc.u = rA[kc]; aF[kc] = fc.v; }
        {
            frag_cast f4;
            if (q == 0)      f4.u = rA4;
            else if (q == 1) f4.u = make_uint4(cvt_pk_bf16(b01.x, b01.y), cvt_pk_bf16(b23.x, b23.y),
                                               cvt_pk_bf16(b45.x, b45.y), cvt_pk_bf16(b67.x, b67.y));
            else if (q == 2) f4.u = make_uint4(cvt_pk_bf16(b01.x, b01.y), cvt_pk_bf16(b23.x, b23.y),
                                               cvt_pk_bf16(b45.x, b45.y), 0u);
            else             f4.u = make_uint4(0u, 0u, 0u, 0u);
            aF[4] = f4.v;
        }

        if (more) {
            const u32* ab = atomBf + (size_t)srB * ATU;
            #pragma unroll
            for (int kc = 0; kc < 4; ++kc)
                rA[kc] = *(const uint4*)(ab + kc * 16 + q * 4);
            if (q == 0) rA4 = *(const uint4*)(ab + 64);
            const float* bp = bond + (size_t)frB * 14;
            if (q == 1) {
                b01 = *(const float2*)(bp + 0); b23 = *(const float2*)(bp + 2);
                b45 = *(const float2*)(bp + 4); b67 = *(const float2*)(bp + 6);
            } else if (q == 2) {
                b01 = *(const float2*)(bp + 8); b23 = *(const float2*)(bp + 10);
                b45 = *(const float2*)(bp + 12);
            }
        }

        u32 zoff = 0;
        asm volatile("" : "+v"(zoff));   // defeat LICM: keep B ds_reads in-loop
        f32x4 acc[8] = {};
        #pragma unroll
        for (int kc = 0; kc < 5; ++kc) {
            const u32* wrow = Wlds + zoff + ln * 96 + (((kc * 4 + q) ^ (ln & 7)) << 2);
            #pragma unroll
            for (int j = 0; j < 8; ++j) {
                bf16x8 b = *(const bf16x8*)(wrow + j * 1536);   // +16 rows * 96 u32
                acc[j] = __builtin_amdgcn_mfma_f32_16x16x32_bf16(aF[kc], b, acc[j], 0, 0, 0);
            }
        }

        #pragma unroll
        for (int r = 0; r < 4; ++r) {
            int wrow = (r == 0) ? stA.x : (r == 1) ? stA.y : (r == 2) ? stA.z : stA.w;
            u32* orow = hout + (size_t)wrow * 64;
            #pragma unroll
            for (int a = 0; a < 4; ++a)
                orow[16 * a + ln] = relu2_pk(acc[2 * a][r], acc[2 * a + 1][r]);
        }

        if (!more) break;
        s = sn;
        stA = stB;
    }
}

// ---------------- k_msg: persistent waves, VMEM-free MFMA loop ----------------
template<bool USEIDX>
__global__ __launch_bounds__(256, 4)
void k_msg_t(const int* __restrict__ sidx, const int* __restrict__ pidx,
             const u32* __restrict__ Wp, const u32* __restrict__ tmp,
             u32* __restrict__ h)
{
    __shared__ u32 Wlds[128 * 64];   // 32 KB; slot phys = slot ^ (row&15)
    const int tid  = threadIdx.x;
    const int lane = tid & 63;
    const int wv   = tid >> 6;
    const int ln   = lane & 15;
    const int q    = lane >> 4;

    {
        const int row = tid >> 1;        // 128 rows, 2 threads/row
        const int half = tid & 1;        // 8 slots of 16 B each
        const int rx = row & 15;
        #pragma unroll
        for (int sl = 0; sl < 8; ++sl) {
            int L = half * 8 + sl;
            int P = L ^ rx;
            *(uint4*)(Wlds + row * 64 + P * 4) = *(const uint4*)(Wp + row * 64 + L * 4);
        }
    }
    __syncthreads();

    const int NT = NE / 16;              // 50000 tiles of 16 rows
    const int stride = gridDim.x * 4;
    const int sb = xcd_swz(blockIdx.x, gridDim.x);
    int s = sb * 4 + wv;
    if (s >= NT) return;

    int4  stA;
    uint4 tv[4], hv[4];

    {
        int p = s * 16 + ln;
        int sr = sidx[p];
        int hr = USEIDX ? pidx[p] : p;
        if (USEIDX) stA = *(const int4*)(pidx + s * 16 + 4 * q);
        const u32* tb = tmp + (size_t)sr * 64 + q * 4;
        const u32* hb = h   + (size_t)hr * 64 + q * 4;
        #pragma unroll
        for (int kc = 0; kc < 4; ++kc) {
            tv[kc] = *(const uint4*)(tb + kc * 16);
            hv[kc] = *(const uint4*)(hb + kc * 16);
        }
    }

    while (true) {
        const int sn = s + stride;
        const bool more = sn < NT;       // wave-uniform

        int srB = 0, hrB = 0;
        int4 stB;
        if (more) {
            int p = sn * 16 + ln;
            srB = sidx[p];
            hrB = USEIDX ? pidx[p] : p;
            if (USEIDX) stB = *(const int4*)(pidx + sn * 16 + 4 * q);
        }

        bf16x8 aF[4];
        #pragma unroll
        for (int kc = 0; kc < 4; ++kc) {
            frag_cast fc;
            fc.u.x = sub2_pk(tv[kc].x, hv[kc].x);
            fc.u.y = sub2_pk(tv[kc].y, hv[kc].y);
            fc.u.z = sub2_pk(tv[kc].z, hv[kc].z);
            fc.u.w = sub2_pk(tv[kc].w, hv[kc].w);
            aF[kc] = fc.v;
        }

        if (more) {
            const u32* tb = tmp + (size_t)srB * 64 + q * 4;
            const u32* hb = h   + (size_t)hrB * 64 + q * 4;
            #pragma unroll
            for (int kc = 0; kc < 4; ++kc) {
                tv[kc] = *(const uint4*)(tb + kc * 16);
                hv[kc] = *(const uint4*)(hb + kc * 16);
            }
        }

        u32 zoff = 0;
        asm volatile("" : "+v"(zoff));   // defeat LICM: keep B ds_reads in-loop
        f32x4 acc[8] = {};
        #pragma unroll
        for (int kc = 0; kc < 4; ++kc) {
            const u32* wrow = Wlds + zoff + ln * 64 + (((kc * 4 + q) ^ ln) << 2);
            #pragma unroll
            for (int j = 0; j < 8; ++j) {
                bf16x8 b = *(const bf16x8*)(wrow + j * 1024);
                acc[j] = __builtin_amdgcn_mfma_f32_16x16x32_bf16(aF[kc], b, acc[j], 0, 0, 0);
            }
        }

        #pragma unroll
        for (int r = 0; r < 4; ++r) {
            int wrow = USEIDX
                ? ((r == 0) ? stA.x : (r == 1) ? stA.y : (r == 2) ? stA.z : stA.w)
                : (s * 16 + 4 * q + r);
            u32* orow = h + (size_t)wrow * 64;
            #pragma unroll
            for (int a = 0; a < 4; ++a)
                orow[16 * a + ln] = relu2_pk(acc[2 * a][r], acc[2 * a + 1][r]);
        }

        if (!more) break;
        s = sn;
        if (USEIDX) stA = stB;
    }
}

// ---------------- k_out: persistent 16-node tiles, VMEM-free MFMA loop ----------------
__global__ __launch_bounds__(256, 2)
void k_out_p(const u32* __restrict__ atomBf, const u32* __restrict__ Wp,
             const u32* __restrict__ tmp, float* __restrict__ out)
{
    __shared__ u32 Wlds[128 * KPU3];   // 75776 B -> 2 blocks/CU
    const int tid  = threadIdx.x;
    const int lane = tid & 63;
    const int wv   = tid >> 6;
    const int ln   = lane & 15;
    const int q    = lane >> 4;

    {
        const int row = tid >> 1;        // 128 rows, 2 threads/row
        const int half = tid & 1;        // 18 slots of 16 B each
        #pragma unroll
        for (int sl = 0; sl < 18; ++sl) {
            int L = half * 18 + sl;      // 0..35
            *(uint4*)(Wlds + row * KPU3 + L * 4) = *(const uint4*)(Wp + row * KPU3 + L * 4);
        }
    }
    __syncthreads();

    const int NT = NN / 16;              // 3125 tiles of 16 nodes
    const int stride = gridDim.x * 4;
    const int sb = xcd_swz(blockIdx.x, gridDim.x);
    int s = sb * 4 + wv;
    if (s >= NT) return;

    uint4 rA[9];
    auto gather = [&](int ss, uint4* r) {
        int n = ss * 16 + ln;
        const u32* ab = atomBf + (size_t)n * ATU;
        const u32* tp = tmp + (size_t)n * 64;
        #pragma unroll
        for (int kc = 0; kc < 4; ++kc)
            r[kc] = *(const uint4*)(ab + kc * 16 + q * 4);
        if (q == 0) {
            r[4] = *(const uint4*)(ab + 64);
            r[5] = *(const uint4*)(tp + 12);
            r[6] = *(const uint4*)(tp + 28);
            r[7] = *(const uint4*)(tp + 44);
            r[8] = *(const uint4*)(tp + 60);
        } else {
            r[4] = *(const uint4*)(tp + (q - 1) * 4);
            r[5] = *(const uint4*)(tp + 12 + q * 4);
            r[6] = *(const uint4*)(tp + 28 + q * 4);
            r[7] = *(const uint4*)(tp + 44 + q * 4);
            r[8] = make_uint4(0u, 0u, 0u, 0u);
        }
    };

    gather(s, rA);

    while (true) {
        const int sn = s + stride;
        const bool more = sn < NT;       // wave-uniform

        bf16x8 aF[9];
        #pragma unroll
        for (int kc = 0; kc < 9; ++kc) { frag_cast fc; fc.u = rA[kc]; aF[kc] = fc.v; }

        if (more) gather(sn, rA);        // prefetch rides through MFMA (LDS B)

        u32 zoff = 0;
        asm volatile("" : "+v"(zoff));   // defeat LICM: keep B ds_reads in-loop
        f32x4 acc[8] = {};
        #pragma unroll
        for (int kc = 0; kc < KC3; ++kc) {
            const u32* wrow = Wlds + zoff + ln * KPU3 + (kc * 4 + q) * 4;
            #pragma unroll
            for (int j = 0; j < 8; ++j) {
                bf16x8 b = *(const bf16x8*)(wrow + j * (16 * KPU3));
                acc[j] = __builtin_amdgcn_mfma_f32_16x16x32_bf16(aF[kc], b, acc[j], 0, 0, 0);
            }
        }

        // store: 16 nodes x 128 f32; channel(a, ln) = 32a + 2ln (+1)
        #pragma unroll
        for (int r = 0; r < 4; ++r) {
            int n = s * 16 + 4 * q + r;
            float2* orow = (float2*)(out + (size_t)n * HID);
            #pragma unroll
            for (int a = 0; a < 4; ++a) {
                float2 v;
                v.x = relu(acc[2 * a][r]);
                v.y = relu(acc[2 * a + 1][r]);
                orow[16 * a + ln] = v;
            }
        }

        if (!more) break;
        s = sn;
    }
}

// ---------------- launch ----------------

extern "C" void kernel_launch(void* const* d_in, const int* in_sizes, int n_in,
                              void* d_out, int out_size, void* d_ws, size_t ws_size,
                              hipStream_t stream) {
    const float* atom = (const float*)d_in[0];   // [50000][133]
    const float* bond = (const float*)d_in[1];   // [800000][14]
    const float* Wi   = (const float*)d_in[2];   // [128][147]
    const float* Wh   = (const float*)d_in[3];   // [128][128]
    const float* Wo   = (const float*)d_in[4];   // [128][261]
    const int*   src  = (const int*)d_in[5]; (void)src;
    const int*   dst  = (const int*)d_in[6];
    const int*   rev  = (const int*)d_in[7];
    float* out = (float*)d_out;

    char* ws = (char*)d_ws;
    size_t off = 0;
    auto take = [&](size_t bytes) { char* p = ws + off; off = (off + bytes + 255) & ~(size_t)255; return p; };
    u32* hbuf   = (u32*)take((size_t)NE * 64 * 4);     // 204.8 MB
    u32* tmp    = (u32*)take((size_t)NN * 64 * 4);     // 12.8 MB
    u32* atomBf = (u32*)take((size_t)NN * ATU * 4);    // 13.6 MB
    int* fidx   = (int*)take((size_t)NE * 4);
    int* sidx   = (int*)take((size_t)NE * 4);
    int* posOf  = (int*)take((size_t)NE * 4);
    int* pidx   = (int*)take((size_t)NE * 4);
    int* cnt    = (int*)take((size_t)NN * 4);
    int* lexc   = (int*)take((size_t)NN * 4);
    int* rowptr = (int*)take((size_t)(NN + 1) * 4);
    int* cursor = (int*)take((size_t)NN * 4);
    int* chunkSum = (int*)take(256 * 4);
    int* chunkOff = (int*)take(256 * 4);
    u32* WiP = (u32*)take(128 * KPU1 * 4);
    u32* WhP = (u32*)take(128 * WHU * 4);
    u32* WoP = (u32*)take(128 * KPU3 * 4);
    // total ~245 MB (round-14 proven footprint)

    cvt_atom<<<2048, 256, 0, stream>>>(atom, atomBf);
    cvt_w<<<48, 256, 0, stream>>>(Wi, WiP, 147, KPU1, 133, 136, 14);
    cvt_w<<<32, 256, 0, stream>>>(Wh, WhP, 128, WHU, 128, 1 << 20, 0);
    cvt_w<<<80, 256, 0, stream>>>(Wo, WoP, 261, KPU3, 133, 136, 128);

    hipMemsetAsync(cnt, 0, (size_t)NN * 4, stream);
    hist<<<1024, 256, 0, stream>>>(dst, cnt);
    scan1<<<NCH, 256, 0, stream>>>(cnt, lexc, chunkSum);
    scan2<<<1, 256, 0, stream>>>(chunkSum, chunkOff);
    scan3<<<NCH, 256, 0, stream>>>(lexc, chunkOff, rowptr, cursor);
    scatter<<<1024, 256, 0, stream>>>(dst, rev, cursor, fidx, sidx, posOf);
    pidx_build<<<1024, 256, 0, stream>>>(fidx, posOf, pidx);

    k_init<<<768, 256, 0, stream>>>(atomBf, bond, fidx, sidx, pidx, WiP, hbuf);   // e-layout
    segsum_t<false><<<2048, 256, 0, stream>>>(rowptr, nullptr, hbuf, tmp);        // sequential
    k_msg_t<false><<<1024, 256, 0, stream>>>(sidx, pidx, WhP, tmp, hbuf);         // all-stream -> f-layout
    segsum_t<true><<<2048, 256, 0, stream>>>(rowptr, pidx, hbuf, tmp);            // gather
    k_msg_t<true><<<1024, 256, 0, stream>>>(sidx, pidx, WhP, tmp, hbuf);          // random rows -> e-layout
    segsum_t<false><<<2048, 256, 0, stream>>>(rowptr, nullptr, hbuf, tmp);        // sequential
    k_out_p<<<512, 256, 0, stream>>>(atomBf, WoP, tmp, out);
}

// Round 14
// 574.635 us; speedup vs baseline: 1.1996x; 1.0109x over previous
//
#include <hip/hip_runtime.h>

// DMPNN encoder, MI355X bf16-MFMA, round 20: exact restore of the measured
// best configuration (r14, 572.7us). r19's XCD swizzle was neutral-to-
// slightly-negative (die-level L3 already provides the targeted locality;
// 4MB per-XCD L2s are too small for the 12.8-25MB shared operands) -> revert.
//
// Pipeline (pos-space, alternating e-/f-layout; identities:
//   fidx[p]=rev[eidx[p]], sidx[p]=dst[eidx[p]] (sorted),
//   pidx[p]=posOf[fidx[p]] fix-point-free involution):
//   k_init : persistent waves, Wi in LDS (96-stride 24-slot XOR), e-layout @pidx[p]
//   segsum1: sequential (e-layout)
//   k_msg1 : tmp[sidx[p]] - h0@p -> h1 f-layout @p
//   segsum2: gather rows pidx[seg]
//   k_msg2 : tmp[sidx[p]] - h1@pidx[p] -> h2 e-layout @pidx[p]
//   segsum3: sequential
//   k_out  : persistent 16-node tiles, Wo in LDS (stride 148 = conflict-free)
//
// Weight channel permutation c(p) = (p&64) + 2*(p&15) + ((p>>4)&1) + 32*((p>>5)&1):
// acc pair (2a,2a+1) at lane ln = channels 32a+2ln, 32a+2ln+1; u32 col u holds
// channels 2u,2u+1 (natural order).

typedef unsigned int u32;
typedef unsigned short u16;
using bf16x8 = __attribute__((ext_vector_type(8))) __bf16;
using f32x4  = __attribute__((ext_vector_type(4))) float;

#define NN 50000
#define NP 400000
#define NE 800000
#define AF 133
#define HID 128
#define ATU 68      // atomBf row stride in u32
#define KPU1 80     // Wi packed row stride in u32 (160 cols = 5 kc chunks)
#define WHU 64      // Wh packed row stride (u32) = 256 B rows
#define KPU3 148    // Wo packed row stride; 144 data u32 = 288 cols = 9 chunks
#define KC3 9
#define NCH 196     // scan chunks of 256 covering NN

__device__ __forceinline__ u16 f2bf(float f) {
    union { float f; u32 u; } x; x.f = f;
    u32 r = x.u + 0x7fffu + ((x.u >> 16) & 1u);   // RNE
    return (u16)(r >> 16);
}
__device__ __forceinline__ float bf2f(u16 b) {
    union { u32 u; float f; } x; x.u = ((u32)b) << 16;
    return x.f;
}
__device__ __forceinline__ float lo16(u32 v) { return bf2f((u16)v); }
__device__ __forceinline__ float hi16(u32 v) { return bf2f((u16)(v >> 16)); }
__device__ __forceinline__ u32 pack2(float a, float b) {
    return (u32)f2bf(a) | ((u32)f2bf(b) << 16);
}
__device__ __forceinline__ float relu(float v) { return v > 0.f ? v : 0.f; }

// single-instruction RNE pack of two f32 -> packed bf16x2 (no builtin on gfx950)
__device__ __forceinline__ u32 cvt_pk_bf16(float lo, float hi) {
    u32 r;
    asm("v_cvt_pk_bf16_f32 %0, %1, %2" : "=v"(r) : "v"(lo), "v"(hi));
    return r;
}
__device__ __forceinline__ float bfLO(u32 v) {
    union { u32 u; float f; } x; x.u = v << 16; return x.f;
}
__device__ __forceinline__ float bfHI(u32 v) {
    union { u32 u; float f; } x; x.u = v & 0xffff0000u; return x.f;
}
__device__ __forceinline__ u32 sub2_pk(u32 t, u32 h) {
    return cvt_pk_bf16(bfLO(t) - bfLO(h), bfHI(t) - bfHI(h));
}
__device__ __forceinline__ u32 relu2_pk(float a, float b) {
    return cvt_pk_bf16(a > 0.f ? a : 0.f, b > 0.f ? b : 0.f);
}

union frag_cast { uint4 u; bf16x8 v; };

// ---------------- precompute kernels ----------------

__global__ void cvt_atom(const float* __restrict__ atom, u32* __restrict__ out) {
    int total = NN * ATU;
    for (int i = blockIdx.x * blockDim.x + threadIdx.x; i < total; i += gridDim.x * blockDim.x) {
        int n = i / ATU;
        int cu = i - n * ATU;
        int k = 2 * cu;
        float f0 = (k < AF) ? atom[n * AF + k] : 0.f;
        float f1 = (k + 1 < AF) ? atom[n * AF + k + 1] : 0.f;
        out[i] = pack2(f0, f1);
    }
}

__device__ __forceinline__ float wcol(const float* W, int n, int Kw, int len1, int off2, int len2, int k) {
    if (k < len1) return W[n * Kw + k];
    int j = k - off2;
    if (j >= 0 && j < len2) return W[n * Kw + len1 + j];
    return 0.f;
}
__global__ void cvt_w(const float* __restrict__ W, u32* __restrict__ out,
                      int Kw, int KpU, int len1, int off2, int len2) {
    int total = 128 * KpU;
    for (int i = blockIdx.x * blockDim.x + threadIdx.x; i < total; i += gridDim.x * blockDim.x) {
        int p = i / KpU;
        int cu = i - p * KpU;
        int t = p & 63;
        int c = (p & 64) + 2 * (t & 15) + ((t >> 4) & 1) + 32 * ((t >> 5) & 1);
        int k = 2 * cu;
        out[i] = pack2(wcol(W, c, Kw, len1, off2, len2, k),
                       wcol(W, c, Kw, len1, off2, len2, k + 1));
    }
}

// ---------------- CSR build ----------------

__global__ void hist(const int* __restrict__ dst, int* __restrict__ cnt) {
    for (int e = blockIdx.x * blockDim.x + threadIdx.x; e < NE; e += gridDim.x * blockDim.x)
        atomicAdd(&cnt[dst[e]], 1);
}

__global__ void scan1(const int* __restrict__ cnt, int* __restrict__ lexc, int* __restrict__ chunkSum) {
    __shared__ int s[256];
    int t = threadIdx.x, idx = blockIdx.x * 256 + t;
    int v = (idx < NN) ? cnt[idx] : 0;
    s[t] = v; __syncthreads();
    for (int off = 1; off < 256; off <<= 1) {
        int x = (t >= off) ? s[t - off] : 0;
        __syncthreads();
        s[t] += x;
        __syncthreads();
    }
    if (idx < NN) lexc[idx] = s[t] - v;
    if (t == 255) chunkSum[blockIdx.x] = s[255];
}

__global__ void scan2(const int* __restrict__ chunkSum, int* __restrict__ chunkOff) {
    __shared__ int s[256];
    int t = threadIdx.x;
    int v = (t < NCH) ? chunkSum[t] : 0;
    s[t] = v; __syncthreads();
    for (int off = 1; off < 256; off <<= 1) {
        int x = (t >= off) ? s[t - off] : 0;
        __syncthreads();
        s[t] += x;
        __syncthreads();
    }
    if (t < NCH) chunkOff[t] = s[t] - v;
}

__global__ void scan3(const int* __restrict__ lexc, const int* __restrict__ chunkOff,
                      int* __restrict__ rowptr, int* __restrict__ cursor) {
    int idx = blockIdx.x * 256 + threadIdx.x;
    if (idx < NN) {
        int v = lexc[idx] + chunkOff[blockIdx.x];
        rowptr[idx] = v;
        cursor[idx] = v;
    }
    if (idx == 0) rowptr[NN] = NE;
}

__global__ void scatter(const int* __restrict__ dst, const int* __restrict__ rev,
                        int* __restrict__ cursor, int* __restrict__ fidx,
                        int* __restrict__ sidx, int* __restrict__ posOf) {
    for (int e = blockIdx.x * blockDim.x + threadIdx.x; e < NE; e += gridDim.x * blockDim.x) {
        int d = dst[e];
        int pos = atomicAdd(&cursor[d], 1);
        fidx[pos] = rev[e];
        sidx[pos] = d;        // = src[fidx[pos]], nondecreasing over pos
        posOf[e] = pos;
    }
}

__global__ void pidx_build(const int* __restrict__ fidx, const int* __restrict__ posOf,
                           int* __restrict__ pidx) {
    for (int p = blockIdx.x * blockDim.x + threadIdx.x; p < NE; p += gridDim.x * blockDim.x)
        pidx[p] = posOf[fidx[p]];
}

// ---------------- segment sum ----------------
template<bool G>
__global__ __launch_bounds__(256)
void segsum_t(const int* __restrict__ rowptr, const int* __restrict__ gat,
              const u32* __restrict__ h, u32* __restrict__ tmp) {
    const int lane = threadIdx.x & 63;
    const int wv = threadIdx.x >> 6;
    const int rsel = lane >> 4;
    const int cg = lane & 15;
    const int nwaves = gridDim.x * 4;
    for (int n = blockIdx.x * 4 + wv; n < NN; n += nwaves) {
        int beg = rowptr[n], end = rowptr[n + 1];
        float a0 = 0, a1 = 0, a2 = 0, a3 = 0, a4 = 0, a5 = 0, a6 = 0, a7 = 0;
        int i = beg;
        for (; i + 8 <= end; i += 8) {
            int rA = G ? gat[i + rsel] : (i + rsel);
            int rB = G ? gat[i + 4 + rsel] : (i + 4 + rsel);
            uint4 hA = *(const uint4*)(h + (size_t)rA * 64 + 4 * cg);
            uint4 hB = *(const uint4*)(h + (size_t)rB * 64 + 4 * cg);
            a0 += lo16(hA.x) + lo16(hB.x); a1 += hi16(hA.x) + hi16(hB.x);
            a2 += lo16(hA.y) + lo16(hB.y); a3 += hi16(hA.y) + hi16(hB.y);
            a4 += lo16(hA.z) + lo16(hB.z); a5 += hi16(hA.z) + hi16(hB.z);
            a6 += lo16(hA.w) + lo16(hB.w); a7 += hi16(hA.w) + hi16(hB.w);
        }
        for (; i < end; i += 4) {
            if (i + rsel < end) {
                int rA = G ? gat[i + rsel] : (i + rsel);
                uint4 hA = *(const uint4*)(h + (size_t)rA * 64 + 4 * cg);
                a0 += lo16(hA.x); a1 += hi16(hA.x);
                a2 += lo16(hA.y); a3 += hi16(hA.y);
                a4 += lo16(hA.z); a5 += hi16(hA.z);
                a6 += lo16(hA.w); a7 += hi16(hA.w);
            }
        }
        a0 += __shfl_xor(a0, 16); a0 += __shfl_xor(a0, 32);
        a1 += __shfl_xor(a1, 16); a1 += __shfl_xor(a1, 32);
        a2 += __shfl_xor(a2, 16); a2 += __shfl_xor(a2, 32);
        a3 += __shfl_xor(a3, 16); a3 += __shfl_xor(a3, 32);
        a4 += __shfl_xor(a4, 16); a4 += __shfl_xor(a4, 32);
        a5 += __shfl_xor(a5, 16); a5 += __shfl_xor(a5, 32);
        a6 += __shfl_xor(a6, 16); a6 += __shfl_xor(a6, 32);
        a7 += __shfl_xor(a7, 16); a7 += __shfl_xor(a7, 32);
        if (rsel == 0) {
            uint4 o;
            o.x = pack2(a0, a1); o.y = pack2(a2, a3);
            o.z = pack2(a4, a5); o.w = pack2(a6, a7);
            *(uint4*)(tmp + (size_t)n * 64 + 4 * cg) = o;
        }
    }
}

// ---------------- k_init: persistent waves, VMEM-free MFMA loop ----------------
__global__ __launch_bounds__(256, 3)
void k_init(const u32* __restrict__ atomBf, const float* __restrict__ bond,
            const int* __restrict__ fidx, const int* __restrict__ sidx,
            const int* __restrict__ pidx, const u32* __restrict__ Wp,
            u32* __restrict__ hout)
{
    __shared__ u32 Wlds[128 * 96];   // 49152 B; phys slot = slot ^ (row&7)
    const int tid  = threadIdx.x;
    const int lane = tid & 63;
    const int wv   = tid >> 6;
    const int ln   = lane & 15;
    const int q    = lane >> 4;

    {
        const int row = tid >> 1;        // 128 rows, 2 threads/row
        const int half = tid & 1;        // 10 slots of 16 B each
        const int rx = row & 7;
        #pragma unroll
        for (int sl = 0; sl < 10; ++sl) {
            int L = half * 10 + sl;      // 0..19
            int P = L ^ rx;              // <= 23, fits 24-slot stride
            *(uint4*)(Wlds + row * 96 + P * 4) = *(const uint4*)(Wp + row * KPU1 + L * 4);
        }
    }
    __syncthreads();

    const int NT = NE / 16;              // 50000 tiles of 16 rows
    const int stride = gridDim.x * 4;
    int s = blockIdx.x * 4 + wv;
    if (s >= NT) return;

    uint4  rA[4];
    uint4  rA4;
    float2 b01, b23, b45, b67;
    int4   stA;

    {
        int p = s * 16 + ln;
        int sr = sidx[p];
        int fr = fidx[p];
        stA = *(const int4*)(pidx + s * 16 + 4 * q);
        const u32* ab = atomBf + (size_t)sr * ATU;
        #pragma unroll
        for (int kc = 0; kc < 4; ++kc)
            rA[kc] = *(const uint4*)(ab + kc * 16 + q * 4);
        if (q == 0) rA4 = *(const uint4*)(ab + 64);
        const float* bp = bond + (size_t)fr * 14;
        if (q == 1) {
            b01 = *(const float2*)(bp + 0); b23 = *(const float2*)(bp + 2);
            b45 = *(const float2*)(bp + 4); b67 = *(const float2*)(bp + 6);
        } else if (q == 2) {
            b01 = *(const float2*)(bp + 8); b23 = *(const float2*)(bp + 10);
            b45 = *(const float2*)(bp + 12);
        }
    }

    while (true) {
        const int sn = s + stride;
        const bool more = sn < NT;       // wave-uniform

        int srB = 0, frB = 0;
        int4 stB;
        if (more) {
            int p = sn * 16 + ln;
            srB = sidx[p];
            frB = fidx[p];
            stB = *(const int4*)(pidx + sn * 16 + 4 * q);
        }

        bf16x8 aF[5];
        #pragma unroll
        for (int kc = 0; kc < 4; ++kc) { frag_cast fc; fc.u = rA[kc]; aF[kc] = fc.v; }
        {
            frag_cast f4;
            if (q == 0)      f4.u = rA4;
            else if (q == 1) f4.u = make_uint4(cvt_pk_bf16(b01.x, b01.y), cvt_pk_bf16(b23.x, b23.y),
                                               cvt_pk_bf16(b45.x, b45.y), cvt_pk_bf16(b67.x, b67.y));
            else if (q == 2) f4.u = make_uint4(cvt_pk_bf16(b01.x, b01.y), cvt_pk_bf16(b23.x, b23.y),
                                               cvt_pk_bf16(b45.x, b45.y), 0u);
            else             f4.u = make_uint4(0u, 0u, 0u, 0u);
            aF[4] = f4.v;
        }

        if (more) {
            const u32* ab = atomBf + (size_t)srB * ATU;
            #pragma unroll
            for (int kc = 0; kc < 4; ++kc)
                rA[kc] = *(const uint4*)(ab + kc * 16 + q * 4);
            if (q == 0) rA4 = *(const uint4*)(ab + 64);
            const float* bp = bond + (size_t)frB * 14;
            if (q == 1) {
                b01 = *(const float2*)(bp + 0); b23 = *(const float2*)(bp + 2);
                b45 = *(const float2*)(bp + 4); b67 = *(const float2*)(bp + 6);
            } else if (q == 2) {
                b01 = *(const float2*)(bp + 8); b23 = *(const float2*)(bp + 10);
                b45 = *(const float2*)(bp + 12);
            }
        }

        u32 zoff = 0;
        asm volatile("" : "+v"(zoff));   // defeat LICM: keep B ds_reads in-loop
        f32x4 acc[8] = {};
        #pragma unroll
        for (int kc = 0; kc < 5; ++kc) {
            const u32* wrow = Wlds + zoff + ln * 96 + (((kc * 4 + q) ^ (ln & 7)) << 2);
            #pragma unroll
            for (int j = 0; j < 8; ++j) {
                bf16x8 b = *(const bf16x8*)(wrow + j * 1536);   // +16 rows * 96 u32
                acc[j] = __builtin_amdgcn_mfma_f32_16x16x32_bf16(aF[kc], b, acc[j], 0, 0, 0);
            }
        }

        #pragma unroll
        for (int r = 0; r < 4; ++r) {
            int wrow = (r == 0) ? stA.x : (r == 1) ? stA.y : (r == 2) ? stA.z : stA.w;
            u32* orow = hout + (size_t)wrow * 64;
            #pragma unroll
            for (int a = 0; a < 4; ++a)
                orow[16 * a + ln] = relu2_pk(acc[2 * a][r], acc[2 * a + 1][r]);
        }

        if (!more) break;
        s = sn;
        stA = stB;
    }
}

// ---------------- k_msg: persistent waves, VMEM-free MFMA loop ----------------
template<bool USEIDX>
__global__ __launch_bounds__(256, 4)
void k_msg_t(const int* __restrict__ sidx, const int* __restrict__ pidx,
             const u32* __restrict__ Wp, const u32* __restrict__ tmp,
             u32* __restrict__ h)
{
    __shared__ u32 Wlds[128 * 64];   // 32 KB; slot phys = slot ^ (row&15)
    const int tid  = threadIdx.x;
    const int lane = tid & 63;
    const int wv   = tid >> 6;
    const int ln   = lane & 15;
    const int q    = lane >> 4;

    {
        const int row = tid >> 1;        // 128 rows, 2 threads/row
        const int half = tid & 1;        // 8 slots of 16 B each
        const int rx = row & 15;
        #pragma unroll
        for (int sl = 0; sl < 8; ++sl) {
            int L = half * 8 + sl;
            int P = L ^ rx;
            *(uint4*)(Wlds + row * 64 + P * 4) = *(const uint4*)(Wp + row * 64 + L * 4);
        }
    }
    __syncthreads();

    const int NT = NE / 16;              // 50000 tiles of 16 rows
    const int stride = gridDim.x * 4;
    int s = blockIdx.x * 4 + wv;
    if (s >= NT) return;

    int4  stA;
    uint4 tv[4], hv[4];

    {
        int p = s * 16 + ln;
        int sr = sidx[p];
        int hr = USEIDX ? pidx[p] : p;
        if (USEIDX) stA = *(const int4*)(pidx + s * 16 + 4 * q);
        const u32* tb = tmp + (size_t)sr * 64 + q * 4;
        const u32* hb = h   + (size_t)hr * 64 + q * 4;
        #pragma unroll
        for (int kc = 0; kc < 4; ++kc) {
            tv[kc] = *(const uint4*)(tb + kc * 16);
            hv[kc] = *(const uint4*)(hb + kc * 16);
        }
    }

    while (true) {
        const int sn = s + stride;
        const bool more = sn < NT;       // wave-uniform

        int srB = 0, hrB = 0;
        int4 stB;
        if (more) {
            int p = sn * 16 + ln;
            srB = sidx[p];
            hrB = USEIDX ? pidx[p] : p;
            if (USEIDX) stB = *(const int4*)(pidx + sn * 16 + 4 * q);
        }

        bf16x8 aF[4];
        #pragma unroll
        for (int kc = 0; kc < 4; ++kc) {
            frag_cast fc;
            fc.u.x = sub2_pk(tv[kc].x, hv[kc].x);
            fc.u.y = sub2_pk(tv[kc].y, hv[kc].y);
            fc.u.z = sub2_pk(tv[kc].z, hv[kc].z);
            fc.u.w = sub2_pk(tv[kc].w, hv[kc].w);
            aF[kc] = fc.v;
        }

        if (more) {
            const u32* tb = tmp + (size_t)srB * 64 + q * 4;
            const u32* hb = h   + (size_t)hrB * 64 + q * 4;
            #pragma unroll
            for (int kc = 0; kc < 4; ++kc) {
                tv[kc] = *(const uint4*)(tb + kc * 16);
                hv[kc] = *(const uint4*)(hb + kc * 16);
            }
        }

        u32 zoff = 0;
        asm volatile("" : "+v"(zoff));   // defeat LICM: keep B ds_reads in-loop
        f32x4 acc[8] = {};
        #pragma unroll
        for (int kc = 0; kc < 4; ++kc) {
            const u32* wrow = Wlds + zoff + ln * 64 + (((kc * 4 + q) ^ ln) << 2);
            #pragma unroll
            for (int j = 0; j < 8; ++j) {
                bf16x8 b = *(const bf16x8*)(wrow + j * 1024);
                acc[j] = __builtin_amdgcn_mfma_f32_16x16x32_bf16(aF[kc], b, acc[j], 0, 0, 0);
            }
        }

        #pragma unroll
        for (int r = 0; r < 4; ++r) {
            int wrow = USEIDX
                ? ((r == 0) ? stA.x : (r == 1) ? stA.y : (r == 2) ? stA.z : stA.w)
                : (s * 16 + 4 * q + r);
            u32* orow = h + (size_t)wrow * 64;
            #pragma unroll
            for (int a = 0; a < 4; ++a)
                orow[16 * a + ln] = relu2_pk(acc[2 * a][r], acc[2 * a + 1][r]);
        }

        if (!more) break;
        s = sn;
        if (USEIDX) stA = stB;
    }
}

// ---------------- k_out: persistent 16-node tiles, VMEM-free MFMA loop ----------------
// A row n = concat(atom 136 cols [atomBf u32 0..67], tmp 128 cols [tmp u32
// 0..63], pad). Wo in LDS stride 148 u32: 148%32=20 -> 16 lanes spread over
// 8 distinct 4-bank spans x2 lanes = conflict-free without swizzle.
__global__ __launch_bounds__(256, 2)
void k_out_p(const u32* __restrict__ atomBf, const u32* __restrict__ Wp,
             const u32* __restrict__ tmp, float* __restrict__ out)
{
    __shared__ u32 Wlds[128 * KPU3];   // 75776 B -> 2 blocks/CU
    const int tid  = threadIdx.x;
    const int lane = tid & 63;
    const int wv   = tid >> 6;
    const int ln   = lane & 15;
    const int q    = lane >> 4;

    {
        const int row = tid >> 1;        // 128 rows, 2 threads/row
        const int half = tid & 1;        // 18 slots of 16 B each
        #pragma unroll
        for (int sl = 0; sl < 18; ++sl) {
            int L = half * 18 + sl;      // 0..35
            *(uint4*)(Wlds + row * KPU3 + L * 4) = *(const uint4*)(Wp + row * KPU3 + L * 4);
        }
    }
    __syncthreads();

    const int NT = NN / 16;              // 3125 tiles of 16 nodes
    const int stride = gridDim.x * 4;
    int s = blockIdx.x * 4 + wv;
    if (s >= NT) return;

    uint4 rA[9];
    auto gather = [&](int ss, uint4* r) {
        int n = ss * 16 + ln;
        const u32* ab = atomBf + (size_t)n * ATU;
        const u32* tp = tmp + (size_t)n * 64;
        #pragma unroll
        for (int kc = 0; kc < 4; ++kc)
            r[kc] = *(const uint4*)(ab + kc * 16 + q * 4);
        if (q == 0) {
            r[4] = *(const uint4*)(ab + 64);
            r[5] = *(const uint4*)(tp + 12);
            r[6] = *(const uint4*)(tp + 28);
            r[7] = *(const uint4*)(tp + 44);
            r[8] = *(const uint4*)(tp + 60);
        } else {
            r[4] = *(const uint4*)(tp + (q - 1) * 4);
            r[5] = *(const uint4*)(tp + 12 + q * 4);
            r[6] = *(const uint4*)(tp + 28 + q * 4);
            r[7] = *(const uint4*)(tp + 44 + q * 4);
            r[8] = make_uint4(0u, 0u, 0u, 0u);
        }
    };

    gather(s, rA);

    while (true) {
        const int sn = s + stride;
        const bool more = sn < NT;       // wave-uniform

        bf16x8 aF[9];
        #pragma unroll
        for (int kc = 0; kc < 9; ++kc) { frag_cast fc; fc.u = rA[kc]; aF[kc] = fc.v; }

        if (more) gather(sn, rA);        // prefetch rides through MFMA (LDS B)

        u32 zoff = 0;
        asm volatile("" : "+v"(zoff));   // defeat LICM: keep B ds_reads in-loop
        f32x4 acc[8] = {};
        #pragma unroll
        for (int kc = 0; kc < KC3; ++kc) {
            const u32* wrow = Wlds + zoff + ln * KPU3 + (kc * 4 + q) * 4;
            #pragma unroll
            for (int j = 0; j < 8; ++j) {
                bf16x8 b = *(const bf16x8*)(wrow + j * (16 * KPU3));
                acc[j] = __builtin_amdgcn_mfma_f32_16x16x32_bf16(aF[kc], b, acc[j], 0, 0, 0);
            }
        }

        // store: 16 nodes x 128 f32; channel(a, ln) = 32a + 2ln (+1)
        #pragma unroll
        for (int r = 0; r < 4; ++r) {
            int n = s * 16 + 4 * q + r;
            float2* orow = (float2*)(out + (size_t)n * HID);
            #pragma unroll
            for (int a = 0; a < 4; ++a) {
                float2 v;
                v.x = relu(acc[2 * a][r]);
                v.y = relu(acc[2 * a + 1][r]);
                orow[16 * a + ln] = v;
            }
        }

        if (!more) break;
        s = sn;
    }
}

// ---------------- launch ----------------

extern "C" void kernel_launch(void* const* d_in, const int* in_sizes, int n_in,
                              void* d_out, int out_size, void* d_ws, size_t ws_size,
                              hipStream_t stream) {
    const float* atom = (const float*)d_in[0];   // [50000][133]
    const float* bond = (const float*)d_in[1];   // [800000][14]
    const float* Wi   = (const float*)d_in[2];   // [128][147]
    const float* Wh   = (const float*)d_in[3];   // [128][128]
    const float* Wo   = (const float*)d_in[4];   // [128][261]
    const int*   src  = (const int*)d_in[5]; (void)src;
    const int*   dst  = (const int*)d_in[6];
    const int*   rev  = (const int*)d_in[7];
    float* out = (float*)d_out;

    char* ws = (char*)d_ws;
    size_t off = 0;
    auto take = [&](size_t bytes) { char* p = ws + off; off = (off + bytes + 255) & ~(size_t)255; return p; };
    u32* hbuf   = (u32*)take((size_t)NE * 64 * 4);     // 204.8 MB
    u32* tmp    = (u32*)take((size_t)NN * 64 * 4);     // 12.8 MB
    u32* atomBf = (u32*)take((size_t)NN * ATU * 4);    // 13.6 MB
    int* fidx   = (int*)take((size_t)NE * 4);
    int* sidx   = (int*)take((size_t)NE * 4);
    int* posOf  = (int*)take((size_t)NE * 4);
    int* pidx   = (int*)take((size_t)NE * 4);
    int* cnt    = (int*)take((size_t)NN * 4);
    int* lexc   = (int*)take((size_t)NN * 4);
    int* rowptr = (int*)take((size_t)(NN + 1) * 4);
    int* cursor = (int*)take((size_t)NN * 4);
    int* chunkSum = (int*)take(256 * 4);
    int* chunkOff = (int*)take(256 * 4);
    u32* WiP = (u32*)take(128 * KPU1 * 4);
    u32* WhP = (u32*)take(128 * WHU * 4);
    u32* WoP = (u32*)take(128 * KPU3 * 4);
    // total ~245 MB (round-14 proven footprint)

    cvt_atom<<<2048, 256, 0, stream>>>(atom, atomBf);
    cvt_w<<<48, 256, 0, stream>>>(Wi, WiP, 147, KPU1, 133, 136, 14);
    cvt_w<<<32, 256, 0, stream>>>(Wh, WhP, 128, WHU, 128, 1 << 20, 0);
    cvt_w<<<80, 256, 0, stream>>>(Wo, WoP, 261, KPU3, 133, 136, 128);

    hipMemsetAsync(cnt, 0, (size_t)NN * 4, stream);
    hist<<<1024, 256, 0, stream>>>(dst, cnt);
    scan1<<<NCH, 256, 0, stream>>>(cnt, lexc, chunkSum);
    scan2<<<1, 256, 0, stream>>>(chunkSum, chunkOff);
    scan3<<<NCH, 256, 0, stream>>>(lexc, chunkOff, rowptr, cursor);
    scatter<<<1024, 256, 0, stream>>>(dst, rev, cursor, fidx, sidx, posOf);
    pidx_build<<<1024, 256, 0, stream>>>(fidx, posOf, pidx);

    k_init<<<768, 256, 0, stream>>>(atomBf, bond, fidx, sidx, pidx, WiP, hbuf);   // e-layout
    segsum_t<false><<<2048, 256, 0, stream>>>(rowptr, nullptr, hbuf, tmp);        // sequential
    k_msg_t<false><<<1024, 256, 0, stream>>>(sidx, pidx, WhP, tmp, hbuf);         // all-stream -> f-layout
    segsum_t<true><<<2048, 256, 0, stream>>>(rowptr, pidx, hbuf, tmp);            // gather
    k_msg_t<true><<<1024, 256, 0, stream>>>(sidx, pidx, WhP, tmp, hbuf);          // random rows -> e-layout
    segsum_t<false><<<2048, 256, 0, stream>>>(rowptr, nullptr, hbuf, tmp);        // sequential
    k_out_p<<<512, 256, 0, stream>>>(atomBf, WoP, tmp, out);
}